// Round 5
// baseline (302.775 us; speedup 1.0000x reference)
//
#include <hip/hip_runtime.h>
#include <math.h>

#define N_NODES 50000
#define N_EDGES 800000
#define NBUCKET 196   // ceil(50000/256), bucket = dst>>8
#define CHUNK 4096
#define NCHUNK 196    // ceil(800000/4096)
#define SCAN_N (NBUCKET * NCHUNK)  // 38416
#define SB_A 151      // ceil(SCAN_N/256)
#define SB_B 196      // ceil(N_NODES/256)
#define EPT 16        // edges per thread in scatter_coarse
#define CAP_FINE 8192
#define MAXEPAD (N_EDGES + N_NODES * 8)

__device__ __forceinline__ int roundup8(int v) { return (v + 7) & ~7; }

// ---------------- block-wide exclusive scan helper ----------------

__device__ __forceinline__ int block_excl_scan(int v, int* wsum) {
    int t = threadIdx.x, lane = t & 63, w = t >> 6;
    int sc = v;
    #pragma unroll
    for (int o = 1; o < 64; o <<= 1) {
        int u = __shfl_up(sc, o, 64);
        if (lane >= o) sc += u;
    }
    if (lane == 63) wsum[w] = sc;
    __syncthreads();
    int add = 0;
    #pragma unroll
    for (int j = 0; j < 4; ++j) if (j < w) add += wsum[j];
    return add + sc - v;  // exclusive
}

// ---------------- pass 1: per-chunk coarse histogram + per-dst counts ----------------

__global__ void hist_kernel(const int* __restrict__ dst, int* __restrict__ h,
                            int* __restrict__ counts) {
    __shared__ int hist[NBUCKET];
    for (int i = threadIdx.x; i < NBUCKET; i += 256) hist[i] = 0;
    __syncthreads();
    int base = blockIdx.x * CHUNK;
    int n = min(CHUNK, N_EDGES - base);
    for (int k = threadIdx.x; k < n; k += 256) {
        int d = dst[base + k];
        atomicAdd(&hist[d >> 8], 1);
        atomicAdd(&counts[d], 1);
    }
    __syncthreads();
    for (int i = threadIdx.x; i < NBUCKET; i += 256)
        h[i * NCHUNK + blockIdx.x] = hist[i];
}

// ---------------- dual-region hierarchical scan ----------------
// region A (blocks 0..SB_A): chunk-histogram h (unpadded ecoarse positions)
// region B (blocks SB_A..SB_A+SB_B): roundup8(counts) -> padded CSR offs

__global__ void scan_blocks_dual(int* __restrict__ h, const int* __restrict__ counts,
                                 int* __restrict__ offs, int* __restrict__ blocksums) {
    __shared__ int wsum[4];
    int bid = blockIdx.x, t = threadIdx.x;
    if (bid < SB_A) {
        int i = bid * 256 + t;
        int v = (i < SCAN_N) ? h[i] : 0;
        int e = block_excl_scan(v, wsum);
        if (i < SCAN_N) h[i] = e;
        if (t == 255) blocksums[bid] = e + v;
    } else {
        int j = (bid - SB_A) * 256 + t;
        int v = (j < N_NODES) ? roundup8(counts[j]) : 0;
        int e = block_excl_scan(v, wsum);
        if (j < N_NODES) offs[j] = e;
        if (t == 255) blocksums[bid] = e + v;
    }
}

__global__ void scan_mid(const int* __restrict__ blocksums, int* __restrict__ blockoffs) {
    __shared__ int wsum[4];
    int base = (blockIdx.x == 0) ? 0 : SB_A;
    int n = (blockIdx.x == 0) ? SB_A : SB_B;
    int t = threadIdx.x;
    int v = (t < n) ? blocksums[base + t] : 0;
    int e = block_excl_scan(v, wsum);
    if (t < n) blockoffs[base + t] = e;
}

__global__ void scan_add_dual(int* __restrict__ h, int* __restrict__ offs,
                              const int* __restrict__ counts,
                              const int* __restrict__ blockoffs) {
    int bid = blockIdx.x, t = threadIdx.x;
    if (bid < SB_A) {
        int i = bid * 256 + t;
        if (i < SCAN_N) h[i] += blockoffs[bid];
    } else {
        int j = (bid - SB_A) * 256 + t;
        if (j < N_NODES) {
            int v = offs[j] + blockoffs[bid];
            offs[j] = v;
            if (j == N_NODES - 1) offs[N_NODES] = v + roundup8(counts[j]);
        }
    }
}

// ---------------- pass 2: register-staged LDS bucket sort, coalesced flush ----------------
// record: x = dst<<16 | src, y = weight bits. bucket = (uint)x >> 24.

__launch_bounds__(256, 4)
__global__ void scatter_coarse(const int* __restrict__ src, const int* __restrict__ dst,
                               const float* __restrict__ ew, const int* __restrict__ hs,
                               int2* __restrict__ ecoarse) {
    __shared__ int cnt[NBUCKET];
    __shared__ int excl[NBUCKET];
    __shared__ int cur[NBUCKET];
    __shared__ int gbase[NBUCKET];
    __shared__ int wsum[4];
    __shared__ int2 stage[CHUNK];

    int t = threadIdx.x;
    int base = blockIdx.x * CHUNK;
    int n = min(CHUNK, N_EDGES - base);

    for (int i = t; i < NBUCKET; i += 256) {
        cnt[i] = 0;
        gbase[i] = hs[i * NCHUNK + blockIdx.x];
    }
    __syncthreads();

    int rx[EPT];
    float rw[EPT];
    #pragma unroll
    for (int j = 0; j < EPT; ++j) {
        int k = t + j * 256;
        if (k < n) {
            int e = base + k;
            int d = dst[e];
            rx[j] = (d << 16) | src[e];
            rw[j] = ew[e];
            atomicAdd(&cnt[d >> 8], 1);
        }
    }
    __syncthreads();

    {
        int v = (t < NBUCKET) ? cnt[t] : 0;
        int e = block_excl_scan(v, wsum);
        if (t < NBUCKET) { excl[t] = e; cur[t] = e; }
    }
    __syncthreads();

    #pragma unroll
    for (int j = 0; j < EPT; ++j) {
        int k = t + j * 256;
        if (k < n) {
            int b = ((unsigned)rx[j]) >> 24;
            int p = atomicAdd(&cur[b], 1);
            stage[p] = make_int2(rx[j], __float_as_int(rw[j]));
        }
    }
    __syncthreads();

    for (int k = t; k < n; k += 256) {
        int2 r = stage[k];
        int b = ((unsigned)r.x) >> 24;
        ecoarse[gbase[b] + (k - excl[b])] = r;
    }
}

// ---------------- pass 3: per-bucket fine sort into PADDED CSR ----------------

__launch_bounds__(256)
__global__ void fine_sort(const int* __restrict__ h, const int* __restrict__ offs,
                          const int2* __restrict__ ecoarse, int2* __restrict__ esrt) {
    int b = blockIdx.x, t = threadIdx.x;
    __shared__ int cur[256];
    __shared__ int2 stage[CAP_FINE];
    int bstartU = h[b * NCHUNK];
    int bendU = (b == NBUCKET - 1) ? N_EDGES : h[(b + 1) * NCHUNK];
    int nbU = bendU - bstartU;
    int P = offs[b << 8];
    int nodeEnd = min((b + 1) << 8, N_NODES);
    int plen = offs[nodeEnd] - P;
    int dstv = (b << 8) + t;
    cur[t] = (dstv < N_NODES) ? offs[dstv] - P : 0;
    __syncthreads();
    if (plen <= CAP_FINE) {
        for (int k = t; k < plen; k += 256) stage[k] = make_int2(0, 0);
        __syncthreads();
        for (int k = t; k < nbU; k += 256) {
            int2 r = ecoarse[bstartU + k];
            int d = (((unsigned)r.x) >> 16) & 255;
            int p = atomicAdd(&cur[d], 1);
            stage[p] = make_int2(r.x & 0xFFFF, r.y);
        }
        __syncthreads();
        for (int k = t; k < plen; k += 256) esrt[P + k] = stage[k];
    } else {  // fallback, never expected
        for (int k = t; k < plen; k += 256) esrt[P + k] = make_int2(0, 0);
        __syncthreads();
        for (int k = t; k < nbU; k += 256) {
            int2 r = ecoarse[bstartU + k];
            int d = (((unsigned)r.x) >> 16) & 255;
            int p = atomicAdd(&cur[d], 1);
            esrt[P + p] = make_int2(r.x & 0xFFFF, r.y);
        }
    }
}

// ---------------- bcast via readlane (VALU pipe) ----------------

__device__ __forceinline__ float bcast(float v, int k) {
    return __int_as_float(__builtin_amdgcn_readlane(__float_as_int(v), k));
}

// ---------------- layer 0 fused: gather(13) + dual-GEMM + bias + relu ----------------

__launch_bounds__(256)
__global__ void layer0_fused(const int* __restrict__ offs, const int2* __restrict__ esrt,
                             const float* __restrict__ x, const float* __restrict__ Wrel,
                             const float* __restrict__ bias, const float* __restrict__ Wroot,
                             float* __restrict__ h0) {
    int wid = (blockIdx.x * blockDim.x + threadIdx.x) >> 6;
    int lane = threadIdx.x & 63;
    float wr[13], wo[13];
    #pragma unroll
    for (int k = 0; k < 13; ++k) {
        wr[k] = Wrel[k * 64 + lane];
        wo[k] = Wroot[k * 64 + lane];
    }
    float bc = bias[lane];
    int q = lane >> 4, f = lane & 15;
    int beg = offs[wid], end = offs[wid + 1];
    float acc = 0.f;
    bool fv = (f < 13);
    for (int i = beg + q; i < end; i += 8) {
        int2 e0 = esrt[i], e1 = esrt[i + 4];
        float v0 = fv ? x[(size_t)e0.x * 13 + f] : 0.f;
        float v1 = fv ? x[(size_t)e1.x * 13 + f] : 0.f;
        acc = fmaf(__int_as_float(e0.y), v0, acc);
        acc = fmaf(__int_as_float(e1.y), v1, acc);
    }
    acc += __shfl_xor(acc, 16, 64);
    acc += __shfl_xor(acc, 32, 64);  // every lane now holds aggr[its f]
    float hv = (lane < 13) ? x[(size_t)wid * 13 + lane] : 0.f;
    float a0 = bc, a1 = 0.f, a2 = 0.f, a3 = 0.f;
    #pragma unroll
    for (int k = 0; k + 2 <= 13; k += 2) {
        a0 = fmaf(bcast(acc, k), wr[k], a0);
        a1 = fmaf(bcast(hv, k), wo[k], a1);
        a2 = fmaf(bcast(acc, k + 1), wr[k + 1], a2);
        a3 = fmaf(bcast(hv, k + 1), wo[k + 1], a3);
    }
    a0 = fmaf(bcast(acc, 12), wr[12], a0);
    a1 = fmaf(bcast(hv, 12), wo[12], a1);
    float o = fmaxf((a0 + a2) + (a1 + a3), 0.f);
    h0[(size_t)wid * 64 + lane] = o;
}

// ---------------- gather DIN=64: quarter-wave float4, branch-free padded loop ----------------

__launch_bounds__(256)
__global__ void gather_aggr64(const int* __restrict__ offs, const int2* __restrict__ esrt,
                              const float* __restrict__ x, float* __restrict__ aggr) {
    int wid = (blockIdx.x * blockDim.x + threadIdx.x) >> 6;
    int lane = threadIdx.x & 63;
    int q = lane >> 4, f4 = lane & 15;
    int beg = offs[wid], end = offs[wid + 1];
    float4 acc = make_float4(0.f, 0.f, 0.f, 0.f);
    for (int i = beg + q; i < end; i += 8) {
        int2 e0 = esrt[i];
        int2 e1 = esrt[i + 4];
        float4 v0 = ((const float4*)(x + (size_t)e0.x * 64))[f4];
        float4 v1 = ((const float4*)(x + (size_t)e1.x * 64))[f4];
        float w0 = __int_as_float(e0.y), w1 = __int_as_float(e1.y);
        acc.x = fmaf(w0, v0.x, acc.x); acc.y = fmaf(w0, v0.y, acc.y);
        acc.z = fmaf(w0, v0.z, acc.z); acc.w = fmaf(w0, v0.w, acc.w);
        acc.x = fmaf(w1, v1.x, acc.x); acc.y = fmaf(w1, v1.y, acc.y);
        acc.z = fmaf(w1, v1.z, acc.z); acc.w = fmaf(w1, v1.w, acc.w);
    }
    acc.x += __shfl_xor(acc.x, 16, 64); acc.y += __shfl_xor(acc.y, 16, 64);
    acc.z += __shfl_xor(acc.z, 16, 64); acc.w += __shfl_xor(acc.w, 16, 64);
    acc.x += __shfl_xor(acc.x, 32, 64); acc.y += __shfl_xor(acc.y, 32, 64);
    acc.z += __shfl_xor(acc.z, 32, 64); acc.w += __shfl_xor(acc.w, 32, 64);
    if (q == 0) ((float4*)(aggr + (size_t)wid * 64))[f4] = acc;
}

// ---------------- dual-GEMM + bias + relu; FINAL variant emits z/root dots ----------------

template <bool FINAL>
__launch_bounds__(256, 2)
__global__ void layer_gemm64(const float* __restrict__ aggr, const float* __restrict__ hin,
                             const float* __restrict__ Wrel, const float* __restrict__ bias,
                             const float* __restrict__ Wroot, float* __restrict__ hout,
                             const float* __restrict__ Wrel4, const float* __restrict__ Wroot4,
                             float* __restrict__ z, float* __restrict__ root,
                             int rows_per_wave) {
    int lane = threadIdx.x & 63;
    int wid = (blockIdx.x * blockDim.x + threadIdx.x) >> 6;
    float wr[64], wo[64];
    #pragma unroll
    for (int k = 0; k < 64; ++k) {
        wr[k] = Wrel[k * 64 + lane];
        wo[k] = Wroot[k * 64 + lane];
    }
    float bc = bias[lane];
    float w4r = 0.f, w4o = 0.f;
    if (FINAL) { w4r = Wrel4[lane]; w4o = Wroot4[lane]; }
    int r0 = wid * rows_per_wave;
    int r1 = min(r0 + rows_per_wave, N_NODES);
    for (int r = r0; r < r1; ++r) {
        float av = aggr[(size_t)r * 64 + lane];
        float hv = hin[(size_t)r * 64 + lane];
        float a0 = bc, a1 = 0.f, a2 = 0.f, a3 = 0.f;
        #pragma unroll
        for (int k = 0; k < 64; k += 2) {
            a0 = fmaf(bcast(av, k), wr[k], a0);
            a1 = fmaf(bcast(hv, k), wo[k], a1);
            a2 = fmaf(bcast(av, k + 1), wr[k + 1], a2);
            a3 = fmaf(bcast(hv, k + 1), wo[k + 1], a3);
        }
        float o = fmaxf((a0 + a2) + (a1 + a3), 0.f);
        if (FINAL) {
            float zz = o * w4r, rr = o * w4o;
            #pragma unroll
            for (int m = 1; m < 64; m <<= 1) {
                zz += __shfl_xor(zz, m, 64);
                rr += __shfl_xor(rr, m, 64);
            }
            if (lane == 0) { z[r] = zz; root[r] = rr; }
        } else {
            hout[(size_t)r * 64 + lane] = o;
        }
    }
}

// ---------------- final scalar aggregation + sigmoid (4 lanes per node) ----------------

__launch_bounds__(256)
__global__ void final_aggr(const int* __restrict__ offs, const int2* __restrict__ esrt,
                           const float* __restrict__ z, const float* __restrict__ root,
                           const float* __restrict__ b4, float* __restrict__ out) {
    int tid = blockIdx.x * blockDim.x + threadIdx.x;
    int node = tid >> 2, g = tid & 3;
    if (node >= N_NODES) return;
    int beg = offs[node], end = offs[node + 1];
    float a = 0.f;
    for (int i = beg + g; i < end; i += 8) {
        int2 e0 = esrt[i], e1 = esrt[i + 4];
        a = fmaf(__int_as_float(e0.y), z[e0.x], a);
        a = fmaf(__int_as_float(e1.y), z[e1.x], a);
    }
    a += __shfl_xor(a, 1, 64);
    a += __shfl_xor(a, 2, 64);
    if (g == 0) {
        float v = a + b4[0] + root[node];
        out[node] = 1.f / (1.f + expf(-v));
    }
}

// ---------------- launch ----------------

extern "C" void kernel_launch(void* const* d_in, const int* in_sizes, int n_in,
                              void* d_out, int out_size, void* d_ws, size_t ws_size,
                              hipStream_t stream) {
    const float* x = (const float*)d_in[0];
    const int* eidx = (const int*)d_in[1];
    const float* ew = (const float*)d_in[2];
    const float* Wrel[5];
    const float* brel[5];
    const float* Wroot[5];
    for (int i = 0; i < 5; ++i) {
        Wrel[i] = (const float*)d_in[3 + 3 * i];
        brel[i] = (const float*)d_in[4 + 3 * i];
        Wroot[i] = (const float*)d_in[5 + 3 * i];
    }
    const int* src = eidx;
    const int* dst = eidx + N_EDGES;
    float* out = (float*)d_out;

    char* ws = (char*)d_ws;
    size_t off = 0;
    auto alloc = [&](size_t bytes) -> void* {
        void* p = ws + off;
        off = (off + bytes + 255) & ~(size_t)255;
        return p;
    };
    int* h = (int*)alloc((size_t)(SCAN_N + 256) * 4);
    int* blocksums = (int*)alloc(512 * 4);
    int* blockoffs = (int*)alloc(512 * 4);
    int* counts = (int*)alloc((size_t)N_NODES * 4);
    int* offs = (int*)alloc((size_t)(N_NODES + 1) * 4);
    int2* esrt = (int2*)alloc((size_t)MAXEPAD * 8);
    float* h0 = (float*)alloc((size_t)N_NODES * 64 * 4);
    float* h1 = (float*)alloc((size_t)N_NODES * 64 * 4);
    float* aggr = (float*)alloc((size_t)N_NODES * 64 * 4);
    float* z = (float*)alloc((size_t)N_NODES * 4);
    float* root = (float*)alloc((size_t)N_NODES * 4);
    int2* ecoarse = (int2*)aggr;  // disjoint lifetime (sort phase only)
    (void)ws_size; (void)in_sizes; (void)n_in; (void)out_size;

    // ---- CSR build: counting sort with padded rows ----
    hipMemsetAsync(counts, 0, (size_t)N_NODES * 4, stream);
    hist_kernel<<<NCHUNK, 256, 0, stream>>>(dst, h, counts);
    scan_blocks_dual<<<SB_A + SB_B, 256, 0, stream>>>(h, counts, offs, blocksums);
    scan_mid<<<2, 256, 0, stream>>>(blocksums, blockoffs);
    scan_add_dual<<<SB_A + SB_B, 256, 0, stream>>>(h, offs, counts, blockoffs);
    scatter_coarse<<<NCHUNK, 256, 0, stream>>>(src, dst, ew, h, ecoarse);
    fine_sort<<<NBUCKET, 256, 0, stream>>>(h, offs, ecoarse, esrt);

    const int NODE_BLOCKS = N_NODES * 64 / 256;  // 12500, exact
    const int RPW = 16;
    const int GB = ((N_NODES + RPW - 1) / RPW + 3) / 4;  // 782

    // ---- layer 0 (fused gather13 + GEMM) ----
    layer0_fused<<<NODE_BLOCKS, 256, 0, stream>>>(offs, esrt, x, Wrel[0], brel[0], Wroot[0], h0);

    // ---- layers 1..2 ----
    gather_aggr64<<<NODE_BLOCKS, 256, 0, stream>>>(offs, esrt, h0, aggr);
    layer_gemm64<false><<<GB, 256, 0, stream>>>(aggr, h0, Wrel[1], brel[1], Wroot[1], h1,
                                                nullptr, nullptr, nullptr, nullptr, RPW);
    gather_aggr64<<<NODE_BLOCKS, 256, 0, stream>>>(offs, esrt, h1, aggr);
    layer_gemm64<false><<<GB, 256, 0, stream>>>(aggr, h1, Wrel[2], brel[2], Wroot[2], h0,
                                                nullptr, nullptr, nullptr, nullptr, RPW);

    // ---- layer 3 + fused layer-4 projections ----
    gather_aggr64<<<NODE_BLOCKS, 256, 0, stream>>>(offs, esrt, h0, aggr);
    layer_gemm64<true><<<GB, 256, 0, stream>>>(aggr, h0, Wrel[3], brel[3], Wroot[3], nullptr,
                                               Wrel[4], Wroot[4], z, root, RPW);

    // ---- layer 4 scalar aggregation + sigmoid ----
    final_aggr<<<(N_NODES * 4 + 255) / 256, 256, 0, stream>>>(offs, esrt, z, root, brel[4], out);
}

// Round 6
// 225.795 us; speedup vs baseline: 1.3409x; 1.3409x over previous
//
#include <hip/hip_runtime.h>
#include <math.h>

#define N_NODES 50000
#define N_EDGES 800000
#define NBUCKET 196   // ceil(50000/256), bucket = dst>>8
#define CHUNK 4096
#define NCHUNK 196    // ceil(800000/4096)
#define SCAN_N (NBUCKET * NCHUNK)  // 38416
#define SB_A 151      // ceil(SCAN_N/256)
#define SB_B 196      // ceil(N_NODES/256)
#define EPT 16        // edges per thread in scatter_coarse
#define CAP_FINE 8192
#define MAXEPAD (N_EDGES + N_NODES * 8)

typedef __attribute__((ext_vector_type(8))) short bf16x8;
typedef __attribute__((ext_vector_type(4))) float f32x4;

__device__ __forceinline__ int roundup8(int v) { return (v + 7) & ~7; }

__device__ __forceinline__ unsigned short bf16rn(float f) {
    unsigned u = __float_as_uint(f);
    u = u + 0x7FFF + ((u >> 16) & 1);
    return (unsigned short)(u >> 16);
}
__device__ __forceinline__ float bf2f(unsigned short h) {
    return __uint_as_float(((unsigned)h) << 16);
}

// ---------------- block-wide exclusive scan helper ----------------

__device__ __forceinline__ int block_excl_scan(int v, int* wsum) {
    int t = threadIdx.x, lane = t & 63, w = t >> 6;
    int sc = v;
    #pragma unroll
    for (int o = 1; o < 64; o <<= 1) {
        int u = __shfl_up(sc, o, 64);
        if (lane >= o) sc += u;
    }
    if (lane == 63) wsum[w] = sc;
    __syncthreads();
    int add = 0;
    #pragma unroll
    for (int j = 0; j < 4; ++j) if (j < w) add += wsum[j];
    return add + sc - v;  // exclusive
}

// ---------------- pass 1: per-chunk coarse histogram + per-dst counts ----------------

__global__ void hist_kernel(const int* __restrict__ dst, int* __restrict__ h,
                            int* __restrict__ counts) {
    __shared__ int hist[NBUCKET];
    for (int i = threadIdx.x; i < NBUCKET; i += 256) hist[i] = 0;
    __syncthreads();
    int base = blockIdx.x * CHUNK;
    int n = min(CHUNK, N_EDGES - base);
    for (int k = threadIdx.x; k < n; k += 256) {
        int d = dst[base + k];
        atomicAdd(&hist[d >> 8], 1);
        atomicAdd(&counts[d], 1);
    }
    __syncthreads();
    for (int i = threadIdx.x; i < NBUCKET; i += 256)
        h[i * NCHUNK + blockIdx.x] = hist[i];
}

// ---------------- dual-region hierarchical scan ----------------

__global__ void scan_blocks_dual(int* __restrict__ h, const int* __restrict__ counts,
                                 int* __restrict__ offs, int* __restrict__ blocksums) {
    __shared__ int wsum[4];
    int bid = blockIdx.x, t = threadIdx.x;
    if (bid < SB_A) {
        int i = bid * 256 + t;
        int v = (i < SCAN_N) ? h[i] : 0;
        int e = block_excl_scan(v, wsum);
        if (i < SCAN_N) h[i] = e;
        if (t == 255) blocksums[bid] = e + v;
    } else {
        int j = (bid - SB_A) * 256 + t;
        int v = (j < N_NODES) ? roundup8(counts[j]) : 0;
        int e = block_excl_scan(v, wsum);
        if (j < N_NODES) offs[j] = e;
        if (t == 255) blocksums[bid] = e + v;
    }
}

__global__ void scan_mid(const int* __restrict__ blocksums, int* __restrict__ blockoffs) {
    __shared__ int wsum[4];
    int base = (blockIdx.x == 0) ? 0 : SB_A;
    int n = (blockIdx.x == 0) ? SB_A : SB_B;
    int t = threadIdx.x;
    int v = (t < n) ? blocksums[base + t] : 0;
    int e = block_excl_scan(v, wsum);
    if (t < n) blockoffs[base + t] = e;
}

__global__ void scan_add_dual(int* __restrict__ h, int* __restrict__ offs,
                              const int* __restrict__ counts,
                              const int* __restrict__ blockoffs) {
    int bid = blockIdx.x, t = threadIdx.x;
    if (bid < SB_A) {
        int i = bid * 256 + t;
        if (i < SCAN_N) h[i] += blockoffs[bid];
    } else {
        int j = (bid - SB_A) * 256 + t;
        if (j < N_NODES) {
            int v = offs[j] + blockoffs[bid];
            offs[j] = v;
            if (j == N_NODES - 1) offs[N_NODES] = v + roundup8(counts[j]);
        }
    }
}

// ---------------- pass 2: register-staged LDS bucket sort, coalesced flush ----------------

__launch_bounds__(256, 4)
__global__ void scatter_coarse(const int* __restrict__ src, const int* __restrict__ dst,
                               const float* __restrict__ ew, const int* __restrict__ hs,
                               int2* __restrict__ ecoarse) {
    __shared__ int cnt[NBUCKET];
    __shared__ int excl[NBUCKET];
    __shared__ int cur[NBUCKET];
    __shared__ int gbase[NBUCKET];
    __shared__ int wsum[4];
    __shared__ int2 stage[CHUNK];

    int t = threadIdx.x;
    int base = blockIdx.x * CHUNK;
    int n = min(CHUNK, N_EDGES - base);

    for (int i = t; i < NBUCKET; i += 256) {
        cnt[i] = 0;
        gbase[i] = hs[i * NCHUNK + blockIdx.x];
    }
    __syncthreads();

    int rx[EPT];
    float rw[EPT];
    #pragma unroll
    for (int j = 0; j < EPT; ++j) {
        int k = t + j * 256;
        if (k < n) {
            int e = base + k;
            int d = dst[e];
            rx[j] = (d << 16) | src[e];
            rw[j] = ew[e];
            atomicAdd(&cnt[d >> 8], 1);
        }
    }
    __syncthreads();

    {
        int v = (t < NBUCKET) ? cnt[t] : 0;
        int e = block_excl_scan(v, wsum);
        if (t < NBUCKET) { excl[t] = e; cur[t] = e; }
    }
    __syncthreads();

    #pragma unroll
    for (int j = 0; j < EPT; ++j) {
        int k = t + j * 256;
        if (k < n) {
            int b = ((unsigned)rx[j]) >> 24;
            int p = atomicAdd(&cur[b], 1);
            stage[p] = make_int2(rx[j], __float_as_int(rw[j]));
        }
    }
    __syncthreads();

    for (int k = t; k < n; k += 256) {
        int2 r = stage[k];
        int b = ((unsigned)r.x) >> 24;
        ecoarse[gbase[b] + (k - excl[b])] = r;
    }
}

// ---------------- pass 3: per-bucket fine sort into PADDED CSR ----------------

__launch_bounds__(256)
__global__ void fine_sort(const int* __restrict__ h, const int* __restrict__ offs,
                          const int2* __restrict__ ecoarse, int2* __restrict__ esrt) {
    int b = blockIdx.x, t = threadIdx.x;
    __shared__ int cur[256];
    __shared__ int2 stage[CAP_FINE];
    int bstartU = h[b * NCHUNK];
    int bendU = (b == NBUCKET - 1) ? N_EDGES : h[(b + 1) * NCHUNK];
    int nbU = bendU - bstartU;
    int P = offs[b << 8];
    int nodeEnd = min((b + 1) << 8, N_NODES);
    int plen = offs[nodeEnd] - P;
    int dstv = (b << 8) + t;
    cur[t] = (dstv < N_NODES) ? offs[dstv] - P : 0;
    __syncthreads();
    if (plen <= CAP_FINE) {
        for (int k = t; k < plen; k += 256) stage[k] = make_int2(0, 0);
        __syncthreads();
        for (int k = t; k < nbU; k += 256) {
            int2 r = ecoarse[bstartU + k];
            int d = (((unsigned)r.x) >> 16) & 255;
            int p = atomicAdd(&cur[d], 1);
            stage[p] = make_int2(r.x & 0xFFFF, r.y);
        }
        __syncthreads();
        for (int k = t; k < plen; k += 256) esrt[P + k] = stage[k];
    } else {  // fallback, never expected
        for (int k = t; k < plen; k += 256) esrt[P + k] = make_int2(0, 0);
        __syncthreads();
        for (int k = t; k < nbU; k += 256) {
            int2 r = ecoarse[bstartU + k];
            int d = (((unsigned)r.x) >> 16) & 255;
            int p = atomicAdd(&cur[d], 1);
            esrt[P + p] = make_int2(r.x & 0xFFFF, r.y);
        }
    }
}

// ---------------- bcast via readlane (VALU pipe) ----------------

__device__ __forceinline__ float bcast(float v, int k) {
    return __int_as_float(__builtin_amdgcn_readlane(__float_as_int(v), k));
}

// ---------------- layer 0 fused: gather(13) + dual-GEMM + bias + relu ----------------

__launch_bounds__(256)
__global__ void layer0_fused(const int* __restrict__ offs, const int2* __restrict__ esrt,
                             const float* __restrict__ x, const float* __restrict__ Wrel,
                             const float* __restrict__ bias, const float* __restrict__ Wroot,
                             float* __restrict__ h0) {
    int wid = (blockIdx.x * blockDim.x + threadIdx.x) >> 6;
    int lane = threadIdx.x & 63;
    float wr[13], wo[13];
    #pragma unroll
    for (int k = 0; k < 13; ++k) {
        wr[k] = Wrel[k * 64 + lane];
        wo[k] = Wroot[k * 64 + lane];
    }
    float bc = bias[lane];
    int q = lane >> 4, f = lane & 15;
    int beg = offs[wid], end = offs[wid + 1];
    float acc = 0.f;
    bool fv = (f < 13);
    for (int i = beg + q; i < end; i += 8) {
        int2 e0 = esrt[i], e1 = esrt[i + 4];
        float v0 = fv ? x[(size_t)e0.x * 13 + f] : 0.f;
        float v1 = fv ? x[(size_t)e1.x * 13 + f] : 0.f;
        acc = fmaf(__int_as_float(e0.y), v0, acc);
        acc = fmaf(__int_as_float(e1.y), v1, acc);
    }
    acc += __shfl_xor(acc, 16, 64);
    acc += __shfl_xor(acc, 32, 64);  // every lane now holds aggr[its f]
    float hv = (lane < 13) ? x[(size_t)wid * 13 + lane] : 0.f;
    float a0 = bc, a1 = 0.f, a2 = 0.f, a3 = 0.f;
    #pragma unroll
    for (int k = 0; k + 2 <= 13; k += 2) {
        a0 = fmaf(bcast(acc, k), wr[k], a0);
        a1 = fmaf(bcast(hv, k), wo[k], a1);
        a2 = fmaf(bcast(acc, k + 1), wr[k + 1], a2);
        a3 = fmaf(bcast(hv, k + 1), wo[k + 1], a3);
    }
    a0 = fmaf(bcast(acc, 12), wr[12], a0);
    a1 = fmaf(bcast(hv, 12), wo[12], a1);
    float o = fmaxf((a0 + a2) + (a1 + a3), 0.f);
    h0[(size_t)wid * 64 + lane] = o;
}

// ---------------- gather DIN=64: quarter-wave float4, branch-free padded loop ----------------

__launch_bounds__(256)
__global__ void gather_aggr64(const int* __restrict__ offs, const int2* __restrict__ esrt,
                              const float* __restrict__ x, float* __restrict__ aggr) {
    int wid = (blockIdx.x * blockDim.x + threadIdx.x) >> 6;
    int lane = threadIdx.x & 63;
    int q = lane >> 4, f4 = lane & 15;
    int beg = offs[wid], end = offs[wid + 1];
    float4 acc = make_float4(0.f, 0.f, 0.f, 0.f);
    for (int i = beg + q; i < end; i += 8) {
        int2 e0 = esrt[i];
        int2 e1 = esrt[i + 4];
        float4 v0 = ((const float4*)(x + (size_t)e0.x * 64))[f4];
        float4 v1 = ((const float4*)(x + (size_t)e1.x * 64))[f4];
        float w0 = __int_as_float(e0.y), w1 = __int_as_float(e1.y);
        acc.x = fmaf(w0, v0.x, acc.x); acc.y = fmaf(w0, v0.y, acc.y);
        acc.z = fmaf(w0, v0.z, acc.z); acc.w = fmaf(w0, v0.w, acc.w);
        acc.x = fmaf(w1, v1.x, acc.x); acc.y = fmaf(w1, v1.y, acc.y);
        acc.z = fmaf(w1, v1.z, acc.z); acc.w = fmaf(w1, v1.w, acc.w);
    }
    acc.x += __shfl_xor(acc.x, 16, 64); acc.y += __shfl_xor(acc.y, 16, 64);
    acc.z += __shfl_xor(acc.z, 16, 64); acc.w += __shfl_xor(acc.w, 16, 64);
    acc.x += __shfl_xor(acc.x, 32, 64); acc.y += __shfl_xor(acc.y, 32, 64);
    acc.z += __shfl_xor(acc.z, 32, 64); acc.w += __shfl_xor(acc.w, 32, 64);
    if (q == 0) ((float4*)(aggr + (size_t)wid * 64))[f4] = acc;
}

// ---------------- MFMA dual-GEMM (split-bf16, fp32-accurate) ----------------
// out = relu(aggr@Wrel + bias + hin@Wroot); FINAL also emits z=out@Wrel4, root=out@Wroot4.
// A,B split: v = hi + lo (bf16 each); A@B = Ah·Bh + Ah·Bl + Al·Bh (error ~2^-17).
// 128 rows/block, 4 waves; wave handles 2 rowgroups of 16 rows; B frags in LDS.

template <bool FINAL>
__launch_bounds__(256)
__global__ void mfma_gemm(const float* __restrict__ aggr, const float* __restrict__ hin,
                          const float* __restrict__ Wrel, const float* __restrict__ bias,
                          const float* __restrict__ Wroot, float* __restrict__ hout,
                          const float* __restrict__ Wrel4, const float* __restrict__ Wroot4,
                          float* __restrict__ z, float* __restrict__ root) {
    __shared__ float wraw[2][64 * 64];
    __shared__ short bfr[32][64][8];   // [frag][lane][8 bf16] ; frag=(((mat*4+ct)*2+ks)*2+hl)
    int t = threadIdx.x;
    int lane = t & 63;

    {   // stage raw fp32 weights, coalesced
        const float4* wr4 = (const float4*)Wrel;
        const float4* wo4 = (const float4*)Wroot;
        float4* d0 = (float4*)&wraw[0][0];
        float4* d1 = (float4*)&wraw[1][0];
        for (int i = t; i < 1024; i += 256) { d0[i] = wr4[i]; d1[i] = wo4[i]; }
    }
    __syncthreads();

    // build split-bf16 B fragments in MFMA layout (read later as stride-16B b128)
    for (int i = 0; i < 4; ++i) {
        int p = (t >> 6) + 4 * i;          // p = mat*8 + ct*2 + ks
        int mat = p >> 3, ct = (p >> 1) & 3, ks = p & 1;
        int col = ct * 16 + (lane & 15);
        int kbase = ks * 32 + (lane >> 4) * 8;
        bf16x8 hv, lv;
        #pragma unroll
        for (int j = 0; j < 8; ++j) {
            float v = wraw[mat][(kbase + j) * 64 + col];
            unsigned short hh = bf16rn(v);
            hv[j] = (short)hh;
            lv[j] = (short)bf16rn(v - bf2f(hh));
        }
        *(bf16x8*)&bfr[p * 2 + 0][lane][0] = hv;
        *(bf16x8*)&bfr[p * 2 + 1][lane][0] = lv;
    }
    __syncthreads();

    float biasr[4], w4r[4], w4o[4];
    #pragma unroll
    for (int ct = 0; ct < 4; ++ct) {
        biasr[ct] = bias[ct * 16 + (lane & 15)];
        if (FINAL) {
            w4r[ct] = Wrel4[ct * 16 + (lane & 15)];
            w4o[ct] = Wroot4[ct * 16 + (lane & 15)];
        }
    }

    int koff = (lane >> 4) * 8;
    #pragma unroll
    for (int g = 0; g < 2; ++g) {
        int rowbase = blockIdx.x * 128 + (t >> 6) * 32 + g * 16;
        int rowA = min(rowbase + (lane & 15), N_NODES - 1);
        bf16x8 Ah[2][2], Al[2][2];
        #pragma unroll
        for (int mat = 0; mat < 2; ++mat) {
            const float* base = (mat == 0 ? aggr : hin) + (size_t)rowA * 64;
            #pragma unroll
            for (int ks = 0; ks < 2; ++ks) {
                float4 v0 = *(const float4*)(base + ks * 32 + koff);
                float4 v1 = *(const float4*)(base + ks * 32 + koff + 4);
                float vv[8] = {v0.x, v0.y, v0.z, v0.w, v1.x, v1.y, v1.z, v1.w};
                bf16x8 ah, al;
                #pragma unroll
                for (int j = 0; j < 8; ++j) {
                    unsigned short hh = bf16rn(vv[j]);
                    ah[j] = (short)hh;
                    al[j] = (short)bf16rn(vv[j] - bf2f(hh));
                }
                Ah[mat][ks] = ah;
                Al[mat][ks] = al;
            }
        }
        f32x4 acc[4];
        #pragma unroll
        for (int ct = 0; ct < 4; ++ct)
            acc[ct] = (f32x4){biasr[ct], biasr[ct], biasr[ct], biasr[ct]};
        #pragma unroll
        for (int mat = 0; mat < 2; ++mat)
        #pragma unroll
        for (int ks = 0; ks < 2; ++ks) {
            bf16x8 ah = Ah[mat][ks], al = Al[mat][ks];
            #pragma unroll
            for (int ct = 0; ct < 4; ++ct) {
                const int fb = ((mat * 4 + ct) * 2 + ks) * 2;
                bf16x8 bh = *(const bf16x8*)&bfr[fb][lane][0];
                bf16x8 bl = *(const bf16x8*)&bfr[fb + 1][lane][0];
                acc[ct] = __builtin_amdgcn_mfma_f32_16x16x32_bf16(ah, bh, acc[ct], 0, 0, 0);
                acc[ct] = __builtin_amdgcn_mfma_f32_16x16x32_bf16(ah, bl, acc[ct], 0, 0, 0);
                acc[ct] = __builtin_amdgcn_mfma_f32_16x16x32_bf16(al, bh, acc[ct], 0, 0, 0);
            }
        }
        if (FINAL) {
            float zz[4] = {0.f, 0.f, 0.f, 0.f}, rr[4] = {0.f, 0.f, 0.f, 0.f};
            #pragma unroll
            for (int ct = 0; ct < 4; ++ct)
            #pragma unroll
            for (int j = 0; j < 4; ++j) {
                float o = fmaxf(acc[ct][j], 0.f);
                zz[j] = fmaf(o, w4r[ct], zz[j]);
                rr[j] = fmaf(o, w4o[ct], rr[j]);
            }
            #pragma unroll
            for (int j = 0; j < 4; ++j) {
                float a = zz[j], b = rr[j];
                #pragma unroll
                for (int m = 1; m < 16; m <<= 1) {
                    a += __shfl_xor(a, m, 64);
                    b += __shfl_xor(b, m, 64);
                }
                int row = rowbase + (lane >> 4) * 4 + j;
                if ((lane & 15) == 0 && row < N_NODES) { z[row] = a; root[row] = b; }
            }
        } else {
            #pragma unroll
            for (int j = 0; j < 4; ++j) {
                int row = rowbase + (lane >> 4) * 4 + j;
                if (row < N_NODES) {
                    #pragma unroll
                    for (int ct = 0; ct < 4; ++ct)
                        hout[(size_t)row * 64 + ct * 16 + (lane & 15)] = fmaxf(acc[ct][j], 0.f);
                }
            }
        }
    }
}

// ---------------- final scalar aggregation + sigmoid (4 lanes per node) ----------------

__launch_bounds__(256)
__global__ void final_aggr(const int* __restrict__ offs, const int2* __restrict__ esrt,
                           const float* __restrict__ z, const float* __restrict__ root,
                           const float* __restrict__ b4, float* __restrict__ out) {
    int tid = blockIdx.x * blockDim.x + threadIdx.x;
    int node = tid >> 2, g = tid & 3;
    if (node >= N_NODES) return;
    int beg = offs[node], end = offs[node + 1];
    float a = 0.f;
    for (int i = beg + g; i < end; i += 8) {
        int2 e0 = esrt[i], e1 = esrt[i + 4];
        a = fmaf(__int_as_float(e0.y), z[e0.x], a);
        a = fmaf(__int_as_float(e1.y), z[e1.x], a);
    }
    a += __shfl_xor(a, 1, 64);
    a += __shfl_xor(a, 2, 64);
    if (g == 0) {
        float v = a + b4[0] + root[node];
        out[node] = 1.f / (1.f + expf(-v));
    }
}

// ---------------- launch ----------------

extern "C" void kernel_launch(void* const* d_in, const int* in_sizes, int n_in,
                              void* d_out, int out_size, void* d_ws, size_t ws_size,
                              hipStream_t stream) {
    const float* x = (const float*)d_in[0];
    const int* eidx = (const int*)d_in[1];
    const float* ew = (const float*)d_in[2];
    const float* Wrel[5];
    const float* brel[5];
    const float* Wroot[5];
    for (int i = 0; i < 5; ++i) {
        Wrel[i] = (const float*)d_in[3 + 3 * i];
        brel[i] = (const float*)d_in[4 + 3 * i];
        Wroot[i] = (const float*)d_in[5 + 3 * i];
    }
    const int* src = eidx;
    const int* dst = eidx + N_EDGES;
    float* out = (float*)d_out;

    char* ws = (char*)d_ws;
    size_t off = 0;
    auto alloc = [&](size_t bytes) -> void* {
        void* p = ws + off;
        off = (off + bytes + 255) & ~(size_t)255;
        return p;
    };
    int* h = (int*)alloc((size_t)(SCAN_N + 256) * 4);
    int* blocksums = (int*)alloc(512 * 4);
    int* blockoffs = (int*)alloc(512 * 4);
    int* counts = (int*)alloc((size_t)N_NODES * 4);
    int* offs = (int*)alloc((size_t)(N_NODES + 1) * 4);
    int2* esrt = (int2*)alloc((size_t)MAXEPAD * 8);
    float* h0 = (float*)alloc((size_t)N_NODES * 64 * 4);
    float* h1 = (float*)alloc((size_t)N_NODES * 64 * 4);
    float* aggr = (float*)alloc((size_t)N_NODES * 64 * 4);
    float* z = (float*)alloc((size_t)N_NODES * 4);
    float* root = (float*)alloc((size_t)N_NODES * 4);
    int2* ecoarse = (int2*)aggr;  // disjoint lifetime (sort phase only)
    (void)ws_size; (void)in_sizes; (void)n_in; (void)out_size;

    // ---- CSR build: counting sort with rows padded to multiple of 8 ----
    hipMemsetAsync(counts, 0, (size_t)N_NODES * 4, stream);
    hist_kernel<<<NCHUNK, 256, 0, stream>>>(dst, h, counts);
    scan_blocks_dual<<<SB_A + SB_B, 256, 0, stream>>>(h, counts, offs, blocksums);
    scan_mid<<<2, 256, 0, stream>>>(blocksums, blockoffs);
    scan_add_dual<<<SB_A + SB_B, 256, 0, stream>>>(h, offs, counts, blockoffs);
    scatter_coarse<<<NCHUNK, 256, 0, stream>>>(src, dst, ew, h, ecoarse);
    fine_sort<<<NBUCKET, 256, 0, stream>>>(h, offs, ecoarse, esrt);

    const int NODE_BLOCKS = N_NODES * 64 / 256;  // 12500, exact
    const int NGB = (N_NODES + 127) / 128;       // 391

    // ---- layer 0 (fused gather13 + GEMM) ----
    layer0_fused<<<NODE_BLOCKS, 256, 0, stream>>>(offs, esrt, x, Wrel[0], brel[0], Wroot[0], h0);

    // ---- layers 1..2 ----
    gather_aggr64<<<NODE_BLOCKS, 256, 0, stream>>>(offs, esrt, h0, aggr);
    mfma_gemm<false><<<NGB, 256, 0, stream>>>(aggr, h0, Wrel[1], brel[1], Wroot[1], h1,
                                              nullptr, nullptr, nullptr, nullptr);
    gather_aggr64<<<NODE_BLOCKS, 256, 0, stream>>>(offs, esrt, h1, aggr);
    mfma_gemm<false><<<NGB, 256, 0, stream>>>(aggr, h1, Wrel[2], brel[2], Wroot[2], h0,
                                              nullptr, nullptr, nullptr, nullptr);

    // ---- layer 3 + fused layer-4 projections ----
    gather_aggr64<<<NODE_BLOCKS, 256, 0, stream>>>(offs, esrt, h0, aggr);
    mfma_gemm<true><<<NGB, 256, 0, stream>>>(aggr, h0, Wrel[3], brel[3], Wroot[3], nullptr,
                                             Wrel[4], Wroot[4], z, root);

    // ---- layer 4 scalar aggregation + sigmoid ----
    final_aggr<<<(N_NODES * 4 + 255) / 256, 256, 0, stream>>>(offs, esrt, z, root, brel[4], out);
}

// Round 7
// 199.462 us; speedup vs baseline: 1.5180x; 1.1320x over previous
//
#include <hip/hip_runtime.h>
#include <math.h>

#define N_NODES 50000
#define N_EDGES 800000
#define NBUCKET 196   // ceil(50000/256), bucket = dst>>8
#define CHUNK 4096
#define NCHUNK 196    // ceil(800000/4096)
#define SCAN_N (NBUCKET * NCHUNK)  // 38416
#define SB_A 151      // ceil(SCAN_N/256)
#define SB_B 196      // ceil(N_NODES/256)
#define EPT 16        // edges per thread in scatter_coarse
#define CAP_FINE 8192
#define MAXEPAD (N_EDGES + N_NODES * 8)

typedef __attribute__((ext_vector_type(8))) _Float16 f16x8;
typedef __attribute__((ext_vector_type(4))) _Float16 f16x4;
typedef __attribute__((ext_vector_type(4))) float f32x4;

__device__ __forceinline__ int roundup8(int v) { return (v + 7) & ~7; }

// ---------------- block-wide exclusive scan helper ----------------

__device__ __forceinline__ int block_excl_scan(int v, int* wsum) {
    int t = threadIdx.x, lane = t & 63, w = t >> 6;
    int sc = v;
    #pragma unroll
    for (int o = 1; o < 64; o <<= 1) {
        int u = __shfl_up(sc, o, 64);
        if (lane >= o) sc += u;
    }
    if (lane == 63) wsum[w] = sc;
    __syncthreads();
    int add = 0;
    #pragma unroll
    for (int j = 0; j < 4; ++j) if (j < w) add += wsum[j];
    return add + sc - v;  // exclusive
}

// ---------------- pass 1: per-chunk coarse histogram + per-dst counts ----------------

__global__ void hist_kernel(const int* __restrict__ dst, int* __restrict__ h,
                            int* __restrict__ counts) {
    __shared__ int hist[NBUCKET];
    for (int i = threadIdx.x; i < NBUCKET; i += 256) hist[i] = 0;
    __syncthreads();
    int base = blockIdx.x * CHUNK;
    int n = min(CHUNK, N_EDGES - base);
    for (int k = threadIdx.x; k < n; k += 256) {
        int d = dst[base + k];
        atomicAdd(&hist[d >> 8], 1);
        atomicAdd(&counts[d], 1);
    }
    __syncthreads();
    for (int i = threadIdx.x; i < NBUCKET; i += 256)
        h[i * NCHUNK + blockIdx.x] = hist[i];
}

// ---------------- dual-region hierarchical scan ----------------

__global__ void scan_blocks_dual(int* __restrict__ h, const int* __restrict__ counts,
                                 int* __restrict__ offs, int* __restrict__ blocksums) {
    __shared__ int wsum[4];
    int bid = blockIdx.x, t = threadIdx.x;
    if (bid < SB_A) {
        int i = bid * 256 + t;
        int v = (i < SCAN_N) ? h[i] : 0;
        int e = block_excl_scan(v, wsum);
        if (i < SCAN_N) h[i] = e;
        if (t == 255) blocksums[bid] = e + v;
    } else {
        int j = (bid - SB_A) * 256 + t;
        int v = (j < N_NODES) ? roundup8(counts[j]) : 0;
        int e = block_excl_scan(v, wsum);
        if (j < N_NODES) offs[j] = e;
        if (t == 255) blocksums[bid] = e + v;
    }
}

__global__ void scan_mid(const int* __restrict__ blocksums, int* __restrict__ blockoffs) {
    __shared__ int wsum[4];
    int base = (blockIdx.x == 0) ? 0 : SB_A;
    int n = (blockIdx.x == 0) ? SB_A : SB_B;
    int t = threadIdx.x;
    int v = (t < n) ? blocksums[base + t] : 0;
    int e = block_excl_scan(v, wsum);
    if (t < n) blockoffs[base + t] = e;
}

__global__ void scan_add_dual(int* __restrict__ h, int* __restrict__ offs,
                              const int* __restrict__ counts,
                              const int* __restrict__ blockoffs) {
    int bid = blockIdx.x, t = threadIdx.x;
    if (bid < SB_A) {
        int i = bid * 256 + t;
        if (i < SCAN_N) h[i] += blockoffs[bid];
    } else {
        int j = (bid - SB_A) * 256 + t;
        if (j < N_NODES) {
            int v = offs[j] + blockoffs[bid];
            offs[j] = v;
            if (j == N_NODES - 1) offs[N_NODES] = v + roundup8(counts[j]);
        }
    }
}

// ---------------- pass 2: register-staged LDS bucket sort, coalesced flush ----------------

__launch_bounds__(256, 4)
__global__ void scatter_coarse(const int* __restrict__ src, const int* __restrict__ dst,
                               const float* __restrict__ ew, const int* __restrict__ hs,
                               int2* __restrict__ ecoarse) {
    __shared__ int cnt[NBUCKET];
    __shared__ int excl[NBUCKET];
    __shared__ int cur[NBUCKET];
    __shared__ int gbase[NBUCKET];
    __shared__ int wsum[4];
    __shared__ int2 stage[CHUNK];

    int t = threadIdx.x;
    int base = blockIdx.x * CHUNK;
    int n = min(CHUNK, N_EDGES - base);

    for (int i = t; i < NBUCKET; i += 256) {
        cnt[i] = 0;
        gbase[i] = hs[i * NCHUNK + blockIdx.x];
    }
    __syncthreads();

    int rx[EPT];
    float rw[EPT];
    #pragma unroll
    for (int j = 0; j < EPT; ++j) {
        int k = t + j * 256;
        if (k < n) {
            int e = base + k;
            int d = dst[e];
            rx[j] = (d << 16) | src[e];
            rw[j] = ew[e];
            atomicAdd(&cnt[d >> 8], 1);
        }
    }
    __syncthreads();

    {
        int v = (t < NBUCKET) ? cnt[t] : 0;
        int e = block_excl_scan(v, wsum);
        if (t < NBUCKET) { excl[t] = e; cur[t] = e; }
    }
    __syncthreads();

    #pragma unroll
    for (int j = 0; j < EPT; ++j) {
        int k = t + j * 256;
        if (k < n) {
            int b = ((unsigned)rx[j]) >> 24;
            int p = atomicAdd(&cur[b], 1);
            stage[p] = make_int2(rx[j], __float_as_int(rw[j]));
        }
    }
    __syncthreads();

    for (int k = t; k < n; k += 256) {
        int2 r = stage[k];
        int b = ((unsigned)r.x) >> 24;
        ecoarse[gbase[b] + (k - excl[b])] = r;
    }
}

// ---------------- pass 3: per-bucket fine sort into PADDED CSR ----------------

__launch_bounds__(256)
__global__ void fine_sort(const int* __restrict__ h, const int* __restrict__ offs,
                          const int2* __restrict__ ecoarse, int2* __restrict__ esrt) {
    int b = blockIdx.x, t = threadIdx.x;
    __shared__ int cur[256];
    __shared__ int2 stage[CAP_FINE];
    int bstartU = h[b * NCHUNK];
    int bendU = (b == NBUCKET - 1) ? N_EDGES : h[(b + 1) * NCHUNK];
    int nbU = bendU - bstartU;
    int P = offs[b << 8];
    int nodeEnd = min((b + 1) << 8, N_NODES);
    int plen = offs[nodeEnd] - P;
    int dstv = (b << 8) + t;
    cur[t] = (dstv < N_NODES) ? offs[dstv] - P : 0;
    __syncthreads();
    if (plen <= CAP_FINE) {
        for (int k = t; k < plen; k += 256) stage[k] = make_int2(0, 0);
        __syncthreads();
        for (int k = t; k < nbU; k += 256) {
            int2 r = ecoarse[bstartU + k];
            int d = (((unsigned)r.x) >> 16) & 255;
            int p = atomicAdd(&cur[d], 1);
            stage[p] = make_int2(r.x & 0xFFFF, r.y);
        }
        __syncthreads();
        for (int k = t; k < plen; k += 256) esrt[P + k] = stage[k];
    } else {  // fallback, never expected
        for (int k = t; k < plen; k += 256) esrt[P + k] = make_int2(0, 0);
        __syncthreads();
        for (int k = t; k < nbU; k += 256) {
            int2 r = ecoarse[bstartU + k];
            int d = (((unsigned)r.x) >> 16) & 255;
            int p = atomicAdd(&cur[d], 1);
            esrt[P + p] = make_int2(r.x & 0xFFFF, r.y);
        }
    }
}

// ---------------- weight pre-conversion to fp16 MFMA fragments ----------------
// frag id = (m*4 + ct)*2 + ks ; entry [frag][lane][8] halves; k = ks*32 + (lane>>4)*8 + j,
// col = ct*16 + (lane&15). Same (lane,reg)->k bijection as the A-side build below.

__global__ void wconv(const float* __restrict__ W1r, const float* __restrict__ W1o,
                      const float* __restrict__ W2r, const float* __restrict__ W2o,
                      const float* __restrict__ W3r, const float* __restrict__ W3o,
                      _Float16* __restrict__ wfrag) {
    int b = blockIdx.x, t = threadIdx.x;
    const float* Wr = (b == 0) ? W1r : (b == 1) ? W2r : W3r;
    const float* Wo = (b == 0) ? W1o : (b == 1) ? W2o : W3o;
    _Float16* out = wfrag + (size_t)b * 8192;
    for (int i = t; i < 1024; i += 256) {
        int frag = i >> 6, lane = i & 63;
        int m = frag >> 3, ct = (frag >> 1) & 3, ks = frag & 1;
        int col = ct * 16 + (lane & 15);
        int kb = ks * 32 + (lane >> 4) * 8;
        const float* W = m ? Wo : Wr;
        f16x8 v;
        #pragma unroll
        for (int j = 0; j < 8; ++j) v[j] = (_Float16)W[(kb + j) * 64 + col];
        *(f16x8*)&out[(size_t)i * 8] = v;
    }
}

// ---------------- bcast via readlane (VALU pipe) ----------------

__device__ __forceinline__ float bcast(float v, int k) {
    return __int_as_float(__builtin_amdgcn_readlane(__float_as_int(v), k));
}

// ---------------- layer 0 fused: gather(13) + dual-GEMM + bias + relu -> fp16 ----------------

__launch_bounds__(256)
__global__ void layer0_fused(const int* __restrict__ offs, const int2* __restrict__ esrt,
                             const float* __restrict__ x, const float* __restrict__ Wrel,
                             const float* __restrict__ bias, const float* __restrict__ Wroot,
                             _Float16* __restrict__ h0) {
    int wid = (blockIdx.x * blockDim.x + threadIdx.x) >> 6;
    int lane = threadIdx.x & 63;
    float wr[13], wo[13];
    #pragma unroll
    for (int k = 0; k < 13; ++k) {
        wr[k] = Wrel[k * 64 + lane];
        wo[k] = Wroot[k * 64 + lane];
    }
    float bc = bias[lane];
    int q = lane >> 4, f = lane & 15;
    int beg = offs[wid], end = offs[wid + 1];
    float acc = 0.f;
    bool fv = (f < 13);
    for (int i = beg + q; i < end; i += 8) {
        int2 e0 = esrt[i], e1 = esrt[i + 4];
        float v0 = fv ? x[(size_t)e0.x * 13 + f] : 0.f;
        float v1 = fv ? x[(size_t)e1.x * 13 + f] : 0.f;
        acc = fmaf(__int_as_float(e0.y), v0, acc);
        acc = fmaf(__int_as_float(e1.y), v1, acc);
    }
    acc += __shfl_xor(acc, 16, 64);
    acc += __shfl_xor(acc, 32, 64);
    float hv = (lane < 13) ? x[(size_t)wid * 13 + lane] : 0.f;
    float a0 = bc, a1 = 0.f, a2 = 0.f, a3 = 0.f;
    #pragma unroll
    for (int k = 0; k + 2 <= 13; k += 2) {
        a0 = fmaf(bcast(acc, k), wr[k], a0);
        a1 = fmaf(bcast(hv, k), wo[k], a1);
        a2 = fmaf(bcast(acc, k + 1), wr[k + 1], a2);
        a3 = fmaf(bcast(hv, k + 1), wo[k + 1], a3);
    }
    a0 = fmaf(bcast(acc, 12), wr[12], a0);
    a1 = fmaf(bcast(hv, 12), wo[12], a1);
    float o = fmaxf((a0 + a2) + (a1 + a3), 0.f);
    h0[(size_t)wid * 64 + lane] = (_Float16)o;
}

// ---------------- fused layer: gather(64,fp16) + split-fp16 MFMA dual-GEMM ----------------
// 32 rows/block: 16 quarter-waves gather 2 nodes each into LDS aggrT (fp32);
// 4 waves then compute out = relu(aggr@Wrel + bias + h@Wroot), wave w = col-tile ct.
// aggr path: A = hi+lo fp16 (2 MFMA); root path: A = stored fp16, exact (1 MFMA).

template <bool FINAL>
__launch_bounds__(256)
__global__ void layer_fused(const int* __restrict__ offs, const int2* __restrict__ esrt,
                            const _Float16* __restrict__ hin, const _Float16* __restrict__ wfrag_l,
                            const float* __restrict__ bias, _Float16* __restrict__ hout,
                            const float* __restrict__ Wrel4, const float* __restrict__ Wroot4,
                            float* __restrict__ z, float* __restrict__ root) {
    __shared__ __align__(16) _Float16 bfrag[16][64][8];  // 16 KB
    __shared__ __align__(16) float aggrT[32][68];        // padded: banks spread
    __shared__ __align__(16) _Float16 hrootT[32][72];    // padded
    __shared__ float zpart[4][32], rpart[4][32];
    int t = threadIdx.x;
    int rowbase = blockIdx.x * 32;

    {   // stage B fragments (16 KB, broadcast from L2)
        const int4* s = (const int4*)wfrag_l;
        int4* d = (int4*)&bfrag[0][0][0];
        #pragma unroll
        for (int i = 0; i < 4; ++i) d[t + 256 * i] = s[t + 256 * i];
    }
    {   // stage this block's own rows for the root path (coalesced)
        int row = t >> 3, c8 = (t & 7) * 8;
        int gr = min(rowbase + row, N_NODES - 1);
        *(int4*)&hrootT[row][c8] = *(const int4*)&hin[(size_t)gr * 64 + c8];
    }

    // ---- gather phase: quarter-wave per node, 4 edges per iteration ----
    int qw = t >> 4, f4 = t & 15;
    #pragma unroll
    for (int rr = 0; rr < 2; ++rr) {
        int node = rowbase + qw + rr * 16;
        float4 acc = make_float4(0.f, 0.f, 0.f, 0.f);
        if (node < N_NODES) {
            int beg = offs[node], end = offs[node + 1];
            for (int i = beg; i < end; i += 4) {
                int2 e0 = esrt[i], e1 = esrt[i + 1], e2 = esrt[i + 2], e3 = esrt[i + 3];
                f16x4 v0 = *((const f16x4*)(hin + (size_t)e0.x * 64) + f4);
                f16x4 v1 = *((const f16x4*)(hin + (size_t)e1.x * 64) + f4);
                f16x4 v2 = *((const f16x4*)(hin + (size_t)e2.x * 64) + f4);
                f16x4 v3 = *((const f16x4*)(hin + (size_t)e3.x * 64) + f4);
                float w0 = __int_as_float(e0.y), w1 = __int_as_float(e1.y);
                float w2 = __int_as_float(e2.y), w3 = __int_as_float(e3.y);
                acc.x = fmaf(w0, (float)v0[0], acc.x); acc.y = fmaf(w0, (float)v0[1], acc.y);
                acc.z = fmaf(w0, (float)v0[2], acc.z); acc.w = fmaf(w0, (float)v0[3], acc.w);
                acc.x = fmaf(w1, (float)v1[0], acc.x); acc.y = fmaf(w1, (float)v1[1], acc.y);
                acc.z = fmaf(w1, (float)v1[2], acc.z); acc.w = fmaf(w1, (float)v1[3], acc.w);
                acc.x = fmaf(w2, (float)v2[0], acc.x); acc.y = fmaf(w2, (float)v2[1], acc.y);
                acc.z = fmaf(w2, (float)v2[2], acc.z); acc.w = fmaf(w2, (float)v2[3], acc.w);
                acc.x = fmaf(w3, (float)v3[0], acc.x); acc.y = fmaf(w3, (float)v3[1], acc.y);
                acc.z = fmaf(w3, (float)v3[2], acc.z); acc.w = fmaf(w3, (float)v3[3], acc.w);
            }
        }
        *(float4*)&aggrT[qw + rr * 16][f4 * 4] = acc;
    }
    __syncthreads();

    // ---- MFMA phase: wave w owns column tile ct=w ----
    int w = t >> 6, lane = t & 63;
    int r = lane & 15, koff = (lane >> 4) * 8;
    float bc = bias[w * 16 + r];
    float w4rv = 0.f, w4ov = 0.f;
    if (FINAL) { w4rv = Wrel4[w * 16 + r]; w4ov = Wroot4[w * 16 + r]; }

    #pragma unroll
    for (int g = 0; g < 2; ++g) {
        int lr = g * 16 + r;
        f16x8 Ah[2], Al[2], Ar[2];
        #pragma unroll
        for (int ks = 0; ks < 2; ++ks) {
            float4 a0 = *(const float4*)&aggrT[lr][ks * 32 + koff];
            float4 a1 = *(const float4*)&aggrT[lr][ks * 32 + koff + 4];
            float vv[8] = {a0.x, a0.y, a0.z, a0.w, a1.x, a1.y, a1.z, a1.w};
            f16x8 hi, lo;
            #pragma unroll
            for (int j = 0; j < 8; ++j) {
                _Float16 hh = (_Float16)vv[j];
                hi[j] = hh;
                lo[j] = (_Float16)(vv[j] - (float)hh);
            }
            Ah[ks] = hi;
            Al[ks] = lo;
            Ar[ks] = *(const f16x8*)&hrootT[lr][ks * 32 + koff];
        }
        f32x4 acc = {bc, bc, bc, bc};
        #pragma unroll
        for (int ks = 0; ks < 2; ++ks) {
            f16x8 br = *(const f16x8*)&bfrag[(0 * 4 + w) * 2 + ks][lane][0];
            f16x8 bo = *(const f16x8*)&bfrag[(1 * 4 + w) * 2 + ks][lane][0];
            acc = __builtin_amdgcn_mfma_f32_16x16x32_f16(Ah[ks], br, acc, 0, 0, 0);
            acc = __builtin_amdgcn_mfma_f32_16x16x32_f16(Al[ks], br, acc, 0, 0, 0);
            acc = __builtin_amdgcn_mfma_f32_16x16x32_f16(Ar[ks], bo, acc, 0, 0, 0);
        }
        if (FINAL) {
            #pragma unroll
            for (int j = 0; j < 4; ++j) {
                float o = fmaxf(acc[j], 0.f);
                float zz = o * w4rv, rv = o * w4ov;
                #pragma unroll
                for (int m = 1; m < 16; m <<= 1) {
                    zz += __shfl_xor(zz, m, 64);
                    rv += __shfl_xor(rv, m, 64);
                }
                if (r == 0) {
                    int lrow = g * 16 + (lane >> 4) * 4 + j;
                    zpart[w][lrow] = zz;
                    rpart[w][lrow] = rv;
                }
            }
        } else {
            #pragma unroll
            for (int j = 0; j < 4; ++j) {
                int row = rowbase + g * 16 + (lane >> 4) * 4 + j;
                if (row < N_NODES)
                    hout[(size_t)row * 64 + w * 16 + r] = (_Float16)fmaxf(acc[j], 0.f);
            }
        }
    }
    if (FINAL) {
        __syncthreads();
        if (t < 32) {
            int row = rowbase + t;
            if (row < N_NODES) {
                z[row] = zpart[0][t] + zpart[1][t] + zpart[2][t] + zpart[3][t];
                root[row] = rpart[0][t] + rpart[1][t] + rpart[2][t] + rpart[3][t];
            }
        }
    }
}

// ---------------- final scalar aggregation + sigmoid (4 lanes per node) ----------------

__launch_bounds__(256)
__global__ void final_aggr(const int* __restrict__ offs, const int2* __restrict__ esrt,
                           const float* __restrict__ z, const float* __restrict__ root,
                           const float* __restrict__ b4, float* __restrict__ out) {
    int tid = blockIdx.x * blockDim.x + threadIdx.x;
    int node = tid >> 2, g = tid & 3;
    if (node >= N_NODES) return;
    int beg = offs[node], end = offs[node + 1];
    float a = 0.f;
    for (int i = beg + g; i < end; i += 8) {
        int2 e0 = esrt[i], e1 = esrt[i + 4];
        a = fmaf(__int_as_float(e0.y), z[e0.x], a);
        a = fmaf(__int_as_float(e1.y), z[e1.x], a);
    }
    a += __shfl_xor(a, 1, 64);
    a += __shfl_xor(a, 2, 64);
    if (g == 0) {
        float v = a + b4[0] + root[node];
        out[node] = 1.f / (1.f + expf(-v));
    }
}

// ---------------- launch ----------------

extern "C" void kernel_launch(void* const* d_in, const int* in_sizes, int n_in,
                              void* d_out, int out_size, void* d_ws, size_t ws_size,
                              hipStream_t stream) {
    const float* x = (const float*)d_in[0];
    const int* eidx = (const int*)d_in[1];
    const float* ew = (const float*)d_in[2];
    const float* Wrel[5];
    const float* brel[5];
    const float* Wroot[5];
    for (int i = 0; i < 5; ++i) {
        Wrel[i] = (const float*)d_in[3 + 3 * i];
        brel[i] = (const float*)d_in[4 + 3 * i];
        Wroot[i] = (const float*)d_in[5 + 3 * i];
    }
    const int* src = eidx;
    const int* dst = eidx + N_EDGES;
    float* out = (float*)d_out;

    char* ws = (char*)d_ws;
    size_t off = 0;
    auto alloc = [&](size_t bytes) -> void* {
        void* p = ws + off;
        off = (off + bytes + 255) & ~(size_t)255;
        return p;
    };
    int* h = (int*)alloc((size_t)(SCAN_N + 256) * 4);
    int* blocksums = (int*)alloc(512 * 4);
    int* blockoffs = (int*)alloc(512 * 4);
    int* counts = (int*)alloc((size_t)N_NODES * 4);
    int* offs = (int*)alloc((size_t)(N_NODES + 1) * 4);
    int2* esrt = (int2*)alloc((size_t)MAXEPAD * 8);
    _Float16* h0 = (_Float16*)alloc((size_t)N_NODES * 64 * 2);
    _Float16* h1 = (_Float16*)alloc((size_t)N_NODES * 64 * 2);
    _Float16* wfrag = (_Float16*)alloc((size_t)3 * 8192 * 2);
    float* z = (float*)alloc((size_t)N_NODES * 4);
    float* root = (float*)alloc((size_t)N_NODES * 4);
    int2* ecoarse = (int2*)h0;  // disjoint lifetime: sort phase only (6.4 MB = h0 size)
    (void)ws_size; (void)in_sizes; (void)n_in; (void)out_size;

    // ---- CSR build: counting sort with rows padded to multiple of 8 ----
    hipMemsetAsync(counts, 0, (size_t)N_NODES * 4, stream);
    hist_kernel<<<NCHUNK, 256, 0, stream>>>(dst, h, counts);
    scan_blocks_dual<<<SB_A + SB_B, 256, 0, stream>>>(h, counts, offs, blocksums);
    scan_mid<<<2, 256, 0, stream>>>(blocksums, blockoffs);
    scan_add_dual<<<SB_A + SB_B, 256, 0, stream>>>(h, offs, counts, blockoffs);
    scatter_coarse<<<NCHUNK, 256, 0, stream>>>(src, dst, ew, h, ecoarse);
    fine_sort<<<NBUCKET, 256, 0, stream>>>(h, offs, ecoarse, esrt);

    // ---- weight fragments (fp16), once ----
    wconv<<<3, 256, 0, stream>>>(Wrel[1], Wroot[1], Wrel[2], Wroot[2], Wrel[3], Wroot[3], wfrag);

    const int NODE_BLOCKS = N_NODES * 64 / 256;  // 12500
    const int FB = (N_NODES + 31) / 32;          // 1563

    // ---- layer 0 (fused gather13 + VALU GEMM) -> h0 fp16 ----
    layer0_fused<<<NODE_BLOCKS, 256, 0, stream>>>(offs, esrt, x, Wrel[0], brel[0], Wroot[0], h0);

    // ---- layers 1..3 fused gather + MFMA ----
    layer_fused<false><<<FB, 256, 0, stream>>>(offs, esrt, h0, wfrag, brel[1], h1,
                                               nullptr, nullptr, nullptr, nullptr);
    layer_fused<false><<<FB, 256, 0, stream>>>(offs, esrt, h1, wfrag + 8192, brel[2], h0,
                                               nullptr, nullptr, nullptr, nullptr);
    layer_fused<true><<<FB, 256, 0, stream>>>(offs, esrt, h0, wfrag + 16384, brel[3], nullptr,
                                              Wrel[4], Wroot[4], z, root);

    // ---- layer 4 scalar aggregation + sigmoid ----
    final_aggr<<<(N_NODES * 4 + 255) / 256, 256, 0, stream>>>(offs, esrt, z, root, brel[4], out);
}

// Round 8
// 193.310 us; speedup vs baseline: 1.5663x; 1.0318x over previous
//
#include <hip/hip_runtime.h>
#include <math.h>

#define N_NODES 50000
#define N_EDGES 800000
#define NBUCKET 196   // ceil(50000/256), bucket = dst>>8
#define CHUNK 4096
#define NCHUNK 196    // ceil(800000/4096)
#define SCAN_N (NBUCKET * NCHUNK)  // 38416
#define SB_A 151      // ceil(SCAN_N/256)
#define SB_B 196      // ceil(N_NODES/256)
#define EPT 16        // edges per thread in scatter_coarse
#define CAP_FINE 8192
#define MAXEPAD (N_EDGES + N_NODES * 4)

typedef __attribute__((ext_vector_type(8))) _Float16 f16x8;
typedef __attribute__((ext_vector_type(4))) float f32x4;

__device__ __forceinline__ int roundup4(int v) { return (v + 3) & ~3; }

// ---------------- block-wide exclusive scan helper ----------------

__device__ __forceinline__ int block_excl_scan(int v, int* wsum) {
    int t = threadIdx.x, lane = t & 63, w = t >> 6;
    int sc = v;
    #pragma unroll
    for (int o = 1; o < 64; o <<= 1) {
        int u = __shfl_up(sc, o, 64);
        if (lane >= o) sc += u;
    }
    if (lane == 63) wsum[w] = sc;
    __syncthreads();
    int add = 0;
    #pragma unroll
    for (int j = 0; j < 4; ++j) if (j < w) add += wsum[j];
    return add + sc - v;  // exclusive
}

// ---------------- pass 1: per-chunk coarse histogram + per-dst counts ----------------

__global__ void hist_kernel(const int* __restrict__ dst, int* __restrict__ h,
                            int* __restrict__ counts) {
    __shared__ int hist[NBUCKET];
    for (int i = threadIdx.x; i < NBUCKET; i += 256) hist[i] = 0;
    __syncthreads();
    int base = blockIdx.x * CHUNK;
    int n = min(CHUNK, N_EDGES - base);
    for (int k = threadIdx.x; k < n; k += 256) {
        int d = dst[base + k];
        atomicAdd(&hist[d >> 8], 1);
        atomicAdd(&counts[d], 1);
    }
    __syncthreads();
    for (int i = threadIdx.x; i < NBUCKET; i += 256)
        h[i * NCHUNK + blockIdx.x] = hist[i];
}

// ---------------- dual-region hierarchical scan ----------------

__global__ void scan_blocks_dual(int* __restrict__ h, const int* __restrict__ counts,
                                 int* __restrict__ offs, int* __restrict__ blocksums) {
    __shared__ int wsum[4];
    int bid = blockIdx.x, t = threadIdx.x;
    if (bid < SB_A) {
        int i = bid * 256 + t;
        int v = (i < SCAN_N) ? h[i] : 0;
        int e = block_excl_scan(v, wsum);
        if (i < SCAN_N) h[i] = e;
        if (t == 255) blocksums[bid] = e + v;
    } else {
        int j = (bid - SB_A) * 256 + t;
        int v = (j < N_NODES) ? roundup4(counts[j]) : 0;
        int e = block_excl_scan(v, wsum);
        if (j < N_NODES) offs[j] = e;
        if (t == 255) blocksums[bid] = e + v;
    }
}

__global__ void scan_mid(const int* __restrict__ blocksums, int* __restrict__ blockoffs) {
    __shared__ int wsum[4];
    int base = (blockIdx.x == 0) ? 0 : SB_A;
    int n = (blockIdx.x == 0) ? SB_A : SB_B;
    int t = threadIdx.x;
    int v = (t < n) ? blocksums[base + t] : 0;
    int e = block_excl_scan(v, wsum);
    if (t < n) blockoffs[base + t] = e;
}

__global__ void scan_add_dual(int* __restrict__ h, int* __restrict__ offs,
                              const int* __restrict__ counts,
                              const int* __restrict__ blockoffs) {
    int bid = blockIdx.x, t = threadIdx.x;
    if (bid < SB_A) {
        int i = bid * 256 + t;
        if (i < SCAN_N) h[i] += blockoffs[bid];
    } else {
        int j = (bid - SB_A) * 256 + t;
        if (j < N_NODES) {
            int v = offs[j] + blockoffs[bid];
            offs[j] = v;
            if (j == N_NODES - 1) offs[N_NODES] = v + roundup4(counts[j]);
        }
    }
}

// ---------------- pass 2: register-staged LDS bucket sort, coalesced flush ----------------

__launch_bounds__(256, 4)
__global__ void scatter_coarse(const int* __restrict__ src, const int* __restrict__ dst,
                               const float* __restrict__ ew, const int* __restrict__ hs,
                               int2* __restrict__ ecoarse) {
    __shared__ int cnt[NBUCKET];
    __shared__ int excl[NBUCKET];
    __shared__ int cur[NBUCKET];
    __shared__ int gbase[NBUCKET];
    __shared__ int wsum[4];
    __shared__ int2 stage[CHUNK];

    int t = threadIdx.x;
    int base = blockIdx.x * CHUNK;
    int n = min(CHUNK, N_EDGES - base);

    for (int i = t; i < NBUCKET; i += 256) {
        cnt[i] = 0;
        gbase[i] = hs[i * NCHUNK + blockIdx.x];
    }
    __syncthreads();

    int rx[EPT];
    float rw[EPT];
    #pragma unroll
    for (int j = 0; j < EPT; ++j) {
        int k = t + j * 256;
        if (k < n) {
            int e = base + k;
            int d = dst[e];
            rx[j] = (d << 16) | src[e];
            rw[j] = ew[e];
            atomicAdd(&cnt[d >> 8], 1);
        }
    }
    __syncthreads();

    {
        int v = (t < NBUCKET) ? cnt[t] : 0;
        int e = block_excl_scan(v, wsum);
        if (t < NBUCKET) { excl[t] = e; cur[t] = e; }
    }
    __syncthreads();

    #pragma unroll
    for (int j = 0; j < EPT; ++j) {
        int k = t + j * 256;
        if (k < n) {
            int b = ((unsigned)rx[j]) >> 24;
            int p = atomicAdd(&cur[b], 1);
            stage[p] = make_int2(rx[j], __float_as_int(rw[j]));
        }
    }
    __syncthreads();

    for (int k = t; k < n; k += 256) {
        int2 r = stage[k];
        int b = ((unsigned)r.x) >> 24;
        ecoarse[gbase[b] + (k - excl[b])] = r;
    }
}

// ---------------- pass 3: per-bucket fine sort into PADDED CSR ----------------

__launch_bounds__(256)
__global__ void fine_sort(const int* __restrict__ h, const int* __restrict__ offs,
                          const int2* __restrict__ ecoarse, int2* __restrict__ esrt) {
    int b = blockIdx.x, t = threadIdx.x;
    __shared__ int cur[256];
    __shared__ int2 stage[CAP_FINE];
    int bstartU = h[b * NCHUNK];
    int bendU = (b == NBUCKET - 1) ? N_EDGES : h[(b + 1) * NCHUNK];
    int nbU = bendU - bstartU;
    int P = offs[b << 8];
    int nodeEnd = min((b + 1) << 8, N_NODES);
    int plen = offs[nodeEnd] - P;
    int dstv = (b << 8) + t;
    cur[t] = (dstv < N_NODES) ? offs[dstv] - P : 0;
    __syncthreads();
    if (plen <= CAP_FINE) {
        for (int k = t; k < plen; k += 256) stage[k] = make_int2(0, 0);
        __syncthreads();
        for (int k = t; k < nbU; k += 256) {
            int2 r = ecoarse[bstartU + k];
            int d = (((unsigned)r.x) >> 16) & 255;
            int p = atomicAdd(&cur[d], 1);
            stage[p] = make_int2(r.x & 0xFFFF, r.y);
        }
        __syncthreads();
        for (int k = t; k < plen; k += 256) esrt[P + k] = stage[k];
    } else {  // fallback, never expected
        for (int k = t; k < plen; k += 256) esrt[P + k] = make_int2(0, 0);
        __syncthreads();
        for (int k = t; k < nbU; k += 256) {
            int2 r = ecoarse[bstartU + k];
            int d = (((unsigned)r.x) >> 16) & 255;
            int p = atomicAdd(&cur[d], 1);
            esrt[P + p] = make_int2(r.x & 0xFFFF, r.y);
        }
    }
}

// ---------------- weight pre-conversion to fp16 MFMA fragments ----------------

__global__ void wconv(const float* __restrict__ W1r, const float* __restrict__ W1o,
                      const float* __restrict__ W2r, const float* __restrict__ W2o,
                      const float* __restrict__ W3r, const float* __restrict__ W3o,
                      _Float16* __restrict__ wfrag) {
    int b = blockIdx.x, t = threadIdx.x;
    const float* Wr = (b == 0) ? W1r : (b == 1) ? W2r : W3r;
    const float* Wo = (b == 0) ? W1o : (b == 1) ? W2o : W3o;
    _Float16* out = wfrag + (size_t)b * 8192;
    for (int i = t; i < 1024; i += 256) {
        int frag = i >> 6, lane = i & 63;
        int m = frag >> 3, ct = (frag >> 1) & 3, ks = frag & 1;
        int col = ct * 16 + (lane & 15);
        int kb = ks * 32 + (lane >> 4) * 8;
        const float* W = m ? Wo : Wr;
        f16x8 v;
        #pragma unroll
        for (int j = 0; j < 8; ++j) v[j] = (_Float16)W[(kb + j) * 64 + col];
        *(f16x8*)&out[(size_t)i * 8] = v;
    }
}

// ---------------- bcast via readlane (VALU pipe) ----------------

__device__ __forceinline__ float bcast(float v, int k) {
    return __int_as_float(__builtin_amdgcn_readlane(__float_as_int(v), k));
}

// ---------------- layer 0 fused: gather(13) + dual-GEMM + bias + relu -> fp16 ----------------

__launch_bounds__(256)
__global__ void layer0_fused(const int* __restrict__ offs, const int2* __restrict__ esrt,
                             const float* __restrict__ x, const float* __restrict__ Wrel,
                             const float* __restrict__ bias, const float* __restrict__ Wroot,
                             _Float16* __restrict__ h0) {
    int wid = (blockIdx.x * blockDim.x + threadIdx.x) >> 6;
    int lane = threadIdx.x & 63;
    float wr[13], wo[13];
    #pragma unroll
    for (int k = 0; k < 13; ++k) {
        wr[k] = Wrel[k * 64 + lane];
        wo[k] = Wroot[k * 64 + lane];
    }
    float bc = bias[lane];
    int q = lane >> 4, f = lane & 15;
    int beg = offs[wid], end = offs[wid + 1];
    float acc = 0.f;
    bool fv = (f < 13);
    int i = beg + q;
    for (; i + 4 < end; i += 8) {
        int2 e0 = esrt[i], e1 = esrt[i + 4];
        float v0 = fv ? x[(size_t)e0.x * 13 + f] : 0.f;
        float v1 = fv ? x[(size_t)e1.x * 13 + f] : 0.f;
        acc = fmaf(__int_as_float(e0.y), v0, acc);
        acc = fmaf(__int_as_float(e1.y), v1, acc);
    }
    if (i < end) {
        int2 e = esrt[i];
        float v = fv ? x[(size_t)e.x * 13 + f] : 0.f;
        acc = fmaf(__int_as_float(e.y), v, acc);
    }
    acc += __shfl_xor(acc, 16, 64);
    acc += __shfl_xor(acc, 32, 64);
    float hv = (lane < 13) ? x[(size_t)wid * 13 + lane] : 0.f;
    float a0 = bc, a1 = 0.f, a2 = 0.f, a3 = 0.f;
    #pragma unroll
    for (int k = 0; k + 2 <= 13; k += 2) {
        a0 = fmaf(bcast(acc, k), wr[k], a0);
        a1 = fmaf(bcast(hv, k), wo[k], a1);
        a2 = fmaf(bcast(acc, k + 1), wr[k + 1], a2);
        a3 = fmaf(bcast(hv, k + 1), wo[k + 1], a3);
    }
    a0 = fmaf(bcast(acc, 12), wr[12], a0);
    a1 = fmaf(bcast(hv, 12), wo[12], a1);
    float o = fmaxf((a0 + a2) + (a1 + a3), 0.f);
    h0[(size_t)wid * 64 + lane] = (_Float16)o;
}

// ---------------- fused layer: paired-row gather(64,fp16) + split-fp16 MFMA dual-GEMM ----
// Gather: quarter-wave per node; per iter 4 edges as 2 pairs; lanes 0-7 read row of the
// even edge, lanes 8-15 the odd edge, f16x8 (16B) each -> 1 VMEM instr per edge.
// Lane l accumulates features (l&7)*8..+8; final shfl_xor(8) completes the sum.

template <bool FINAL>
__launch_bounds__(256)
__global__ void layer_fused(const int* __restrict__ offs, const int2* __restrict__ esrt,
                            const _Float16* __restrict__ hin, const _Float16* __restrict__ wfrag_l,
                            const float* __restrict__ bias, _Float16* __restrict__ hout,
                            const float* __restrict__ Wrel4, const float* __restrict__ Wroot4,
                            float* __restrict__ z, float* __restrict__ root) {
    __shared__ __align__(16) _Float16 bfrag[16][64][8];  // 16 KB
    __shared__ __align__(16) float aggrT[32][68];        // padded
    __shared__ __align__(16) _Float16 hrootT[32][72];    // padded
    __shared__ float zpart[4][32], rpart[4][32];
    int t = threadIdx.x;
    int rowbase = blockIdx.x * 32;

    {   // stage B fragments (16 KB, broadcast from L2)
        const int4* s = (const int4*)wfrag_l;
        int4* d = (int4*)&bfrag[0][0][0];
        #pragma unroll
        for (int i = 0; i < 4; ++i) d[t + 256 * i] = s[t + 256 * i];
    }
    {   // stage this block's own rows for the root path (coalesced)
        int row = t >> 3, c8 = (t & 7) * 8;
        int gr = min(rowbase + row, N_NODES - 1);
        *(int4*)&hrootT[row][c8] = *(const int4*)&hin[(size_t)gr * 64 + c8];
    }

    // ---- gather phase ----
    int qw = t >> 4, l = t & 15;
    int hi8 = l >> 3, f8 = l & 7;       // hi8: which edge of the pair this lane reads
    #pragma unroll
    for (int rr = 0; rr < 2; ++rr) {
        int node = rowbase + qw + rr * 16;
        float a[8] = {0.f, 0.f, 0.f, 0.f, 0.f, 0.f, 0.f, 0.f};
        if (node < N_NODES) {
            int beg = offs[node], end = offs[node + 1];
            for (int i = beg; i < end; i += 4) {
                int4 p0 = *(const int4*)(esrt + i);       // edges i, i+1
                int4 p1 = *(const int4*)(esrt + i + 2);   // edges i+2, i+3
                int s0 = hi8 ? p0.z : p0.x;
                int s1 = hi8 ? p1.z : p1.x;
                float w0 = __int_as_float(hi8 ? p0.w : p0.y);
                float w1 = __int_as_float(hi8 ? p1.w : p1.y);
                f16x8 r0 = *(const f16x8*)(hin + (size_t)s0 * 64 + f8 * 8);
                f16x8 r1 = *(const f16x8*)(hin + (size_t)s1 * 64 + f8 * 8);
                #pragma unroll
                for (int j = 0; j < 8; ++j) {
                    a[j] = fmaf(w0, (float)r0[j], a[j]);
                    a[j] = fmaf(w1, (float)r1[j], a[j]);
                }
            }
        }
        #pragma unroll
        for (int j = 0; j < 8; ++j) a[j] += __shfl_xor(a[j], 8, 64);
        // lane l writes float4 = a[hi8*4..+4] at feature col f8*8 + hi8*4
        float4 wv = make_float4(a[hi8 * 4 + 0], a[hi8 * 4 + 1], a[hi8 * 4 + 2], a[hi8 * 4 + 3]);
        *(float4*)&aggrT[qw + rr * 16][f8 * 8 + hi8 * 4] = wv;
    }
    __syncthreads();

    // ---- MFMA phase: wave w owns column tile ct=w ----
    int w = t >> 6, lane = t & 63;
    int r = lane & 15, koff = (lane >> 4) * 8;
    float bc = bias[w * 16 + r];
    float w4rv = 0.f, w4ov = 0.f;
    if (FINAL) { w4rv = Wrel4[w * 16 + r]; w4ov = Wroot4[w * 16 + r]; }

    #pragma unroll
    for (int g = 0; g < 2; ++g) {
        int lr = g * 16 + r;
        f16x8 Ah[2], Al[2], Ar[2];
        #pragma unroll
        for (int ks = 0; ks < 2; ++ks) {
            float4 a0 = *(const float4*)&aggrT[lr][ks * 32 + koff];
            float4 a1 = *(const float4*)&aggrT[lr][ks * 32 + koff + 4];
            float vv[8] = {a0.x, a0.y, a0.z, a0.w, a1.x, a1.y, a1.z, a1.w};
            f16x8 hi, lo;
            #pragma unroll
            for (int j = 0; j < 8; ++j) {
                _Float16 hh = (_Float16)vv[j];
                hi[j] = hh;
                lo[j] = (_Float16)(vv[j] - (float)hh);
            }
            Ah[ks] = hi;
            Al[ks] = lo;
            Ar[ks] = *(const f16x8*)&hrootT[lr][ks * 32 + koff];
        }
        f32x4 acc = {bc, bc, bc, bc};
        #pragma unroll
        for (int ks = 0; ks < 2; ++ks) {
            f16x8 br = *(const f16x8*)&bfrag[(0 * 4 + w) * 2 + ks][lane][0];
            f16x8 bo = *(const f16x8*)&bfrag[(1 * 4 + w) * 2 + ks][lane][0];
            acc = __builtin_amdgcn_mfma_f32_16x16x32_f16(Ah[ks], br, acc, 0, 0, 0);
            acc = __builtin_amdgcn_mfma_f32_16x16x32_f16(Al[ks], br, acc, 0, 0, 0);
            acc = __builtin_amdgcn_mfma_f32_16x16x32_f16(Ar[ks], bo, acc, 0, 0, 0);
        }
        if (FINAL) {
            #pragma unroll
            for (int j = 0; j < 4; ++j) {
                float o = fmaxf(acc[j], 0.f);
                float zz = o * w4rv, rv = o * w4ov;
                #pragma unroll
                for (int m = 1; m < 16; m <<= 1) {
                    zz += __shfl_xor(zz, m, 64);
                    rv += __shfl_xor(rv, m, 64);
                }
                if (r == 0) {
                    int lrow = g * 16 + (lane >> 4) * 4 + j;
                    zpart[w][lrow] = zz;
                    rpart[w][lrow] = rv;
                }
            }
        } else {
            #pragma unroll
            for (int j = 0; j < 4; ++j) {
                int row = rowbase + g * 16 + (lane >> 4) * 4 + j;
                if (row < N_NODES)
                    hout[(size_t)row * 64 + w * 16 + r] = (_Float16)fmaxf(acc[j], 0.f);
            }
        }
    }
    if (FINAL) {
        __syncthreads();
        if (t < 32) {
            int row = rowbase + t;
            if (row < N_NODES) {
                z[row] = zpart[0][t] + zpart[1][t] + zpart[2][t] + zpart[3][t];
                root[row] = rpart[0][t] + rpart[1][t] + rpart[2][t] + rpart[3][t];
            }
        }
    }
}

// ---------------- final scalar aggregation + sigmoid (4 lanes per node) ----------------

__launch_bounds__(256)
__global__ void final_aggr(const int* __restrict__ offs, const int2* __restrict__ esrt,
                           const float* __restrict__ z, const float* __restrict__ root,
                           const float* __restrict__ b4, float* __restrict__ out) {
    int tid = blockIdx.x * blockDim.x + threadIdx.x;
    int node = tid >> 2, g = tid & 3;
    if (node >= N_NODES) return;
    int beg = offs[node], end = offs[node + 1];
    float a = 0.f;
    int i = beg + g;
    for (; i + 4 < end; i += 8) {
        int2 e0 = esrt[i], e1 = esrt[i + 4];
        a = fmaf(__int_as_float(e0.y), z[e0.x], a);
        a = fmaf(__int_as_float(e1.y), z[e1.x], a);
    }
    if (i < end) {
        int2 e = esrt[i];
        a = fmaf(__int_as_float(e.y), z[e.x], a);
    }
    a += __shfl_xor(a, 1, 64);
    a += __shfl_xor(a, 2, 64);
    if (g == 0) {
        float v = a + b4[0] + root[node];
        out[node] = 1.f / (1.f + expf(-v));
    }
}

// ---------------- launch ----------------

extern "C" void kernel_launch(void* const* d_in, const int* in_sizes, int n_in,
                              void* d_out, int out_size, void* d_ws, size_t ws_size,
                              hipStream_t stream) {
    const float* x = (const float*)d_in[0];
    const int* eidx = (const int*)d_in[1];
    const float* ew = (const float*)d_in[2];
    const float* Wrel[5];
    const float* brel[5];
    const float* Wroot[5];
    for (int i = 0; i < 5; ++i) {
        Wrel[i] = (const float*)d_in[3 + 3 * i];
        brel[i] = (const float*)d_in[4 + 3 * i];
        Wroot[i] = (const float*)d_in[5 + 3 * i];
    }
    const int* src = eidx;
    const int* dst = eidx + N_EDGES;
    float* out = (float*)d_out;

    char* ws = (char*)d_ws;
    size_t off = 0;
    auto alloc = [&](size_t bytes) -> void* {
        void* p = ws + off;
        off = (off + bytes + 255) & ~(size_t)255;
        return p;
    };
    int* h = (int*)alloc((size_t)(SCAN_N + 256) * 4);
    int* blocksums = (int*)alloc(512 * 4);
    int* blockoffs = (int*)alloc(512 * 4);
    int* counts = (int*)alloc((size_t)N_NODES * 4);
    int* offs = (int*)alloc((size_t)(N_NODES + 1) * 4);
    int2* esrt = (int2*)alloc((size_t)MAXEPAD * 8);
    _Float16* h0 = (_Float16*)alloc((size_t)N_NODES * 64 * 2);
    _Float16* h1 = (_Float16*)alloc((size_t)N_NODES * 64 * 2);
    _Float16* wfrag = (_Float16*)alloc((size_t)3 * 8192 * 2);
    float* z = (float*)alloc((size_t)N_NODES * 4);
    float* root = (float*)alloc((size_t)N_NODES * 4);
    int2* ecoarse = (int2*)h0;  // disjoint lifetime: sort phase only
    (void)ws_size; (void)in_sizes; (void)n_in; (void)out_size;

    // ---- CSR build: counting sort with rows padded to multiple of 4 ----
    hipMemsetAsync(counts, 0, (size_t)N_NODES * 4, stream);
    hist_kernel<<<NCHUNK, 256, 0, stream>>>(dst, h, counts);
    scan_blocks_dual<<<SB_A + SB_B, 256, 0, stream>>>(h, counts, offs, blocksums);
    scan_mid<<<2, 256, 0, stream>>>(blocksums, blockoffs);
    scan_add_dual<<<SB_A + SB_B, 256, 0, stream>>>(h, offs, counts, blockoffs);
    scatter_coarse<<<NCHUNK, 256, 0, stream>>>(src, dst, ew, h, ecoarse);
    fine_sort<<<NBUCKET, 256, 0, stream>>>(h, offs, ecoarse, esrt);

    // ---- weight fragments (fp16), once ----
    wconv<<<3, 256, 0, stream>>>(Wrel[1], Wroot[1], Wrel[2], Wroot[2], Wrel[3], Wroot[3], wfrag);

    const int NODE_BLOCKS = N_NODES * 64 / 256;  // 12500
    const int FB = (N_NODES + 31) / 32;          // 1563

    // ---- layer 0 (fused gather13 + VALU GEMM) -> h0 fp16 ----
    layer0_fused<<<NODE_BLOCKS, 256, 0, stream>>>(offs, esrt, x, Wrel[0], brel[0], Wroot[0], h0);

    // ---- layers 1..3 fused gather + MFMA ----
    layer_fused<false><<<FB, 256, 0, stream>>>(offs, esrt, h0, wfrag, brel[1], h1,
                                               nullptr, nullptr, nullptr, nullptr);
    layer_fused<false><<<FB, 256, 0, stream>>>(offs, esrt, h1, wfrag + 8192, brel[2], h0,
                                               nullptr, nullptr, nullptr, nullptr);
    layer_fused<true><<<FB, 256, 0, stream>>>(offs, esrt, h0, wfrag + 16384, brel[3], nullptr,
                                              Wrel[4], Wroot[4], z, root);

    // ---- layer 4 scalar aggregation + sigmoid ----
    final_aggr<<<(N_NODES * 4 + 255) / 256, 256, 0, stream>>>(offs, esrt, z, root, brel[4], out);
}

// Round 9
// 181.876 us; speedup vs baseline: 1.6647x; 1.0629x over previous
//
#include <hip/hip_runtime.h>
#include <math.h>

#define N_NODES 50000
#define N_EDGES 800000
#define NBUCKET 196   // ceil(50000/256), bucket = dst>>8
#define CHUNK 4096
#define NCHUNK 196    // ceil(800000/4096)
#define SCAN_N (NBUCKET * NCHUNK)  // 38416
#define SB_A 151      // ceil(SCAN_N/256)
#define SB_B 196      // ceil(N_NODES/256)
#define EPT 16        // edges per thread in scatter_coarse
#define CAP_FINE 8192
#define MAXEPAD (N_EDGES + N_NODES * 4)

typedef __attribute__((ext_vector_type(8))) _Float16 f16x8;
typedef __attribute__((ext_vector_type(4))) float f32x4;

__device__ __forceinline__ int roundup4(int v) { return (v + 3) & ~3; }

// ---------------- block-wide exclusive scan helper ----------------

__device__ __forceinline__ int block_excl_scan(int v, int* wsum) {
    int t = threadIdx.x, lane = t & 63, w = t >> 6;
    int sc = v;
    #pragma unroll
    for (int o = 1; o < 64; o <<= 1) {
        int u = __shfl_up(sc, o, 64);
        if (lane >= o) sc += u;
    }
    if (lane == 63) wsum[w] = sc;
    __syncthreads();
    int add = 0;
    #pragma unroll
    for (int j = 0; j < 4; ++j) if (j < w) add += wsum[j];
    return add + sc - v;  // exclusive
}

// ---------------- pass 1: per-chunk coarse histogram + per-dst counts (+ fused wconv) ----

__global__ void hist_kernel(const int* __restrict__ dst, int* __restrict__ h,
                            int* __restrict__ counts,
                            const float* __restrict__ W1r, const float* __restrict__ W1o,
                            const float* __restrict__ W2r, const float* __restrict__ W2o,
                            const float* __restrict__ W3r, const float* __restrict__ W3o,
                            _Float16* __restrict__ wfrag) {
    if (blockIdx.x >= NCHUNK) {
        // ---- weight pre-conversion to fp16 MFMA fragments (3 blocks) ----
        int b = blockIdx.x - NCHUNK, t = threadIdx.x;
        const float* Wr = (b == 0) ? W1r : (b == 1) ? W2r : W3r;
        const float* Wo = (b == 0) ? W1o : (b == 1) ? W2o : W3o;
        _Float16* out = wfrag + (size_t)b * 8192;
        for (int i = t; i < 1024; i += 256) {
            int frag = i >> 6, lane = i & 63;
            int m = frag >> 3, ct = (frag >> 1) & 3, ks = frag & 1;
            int col = ct * 16 + (lane & 15);
            int kb = ks * 32 + (lane >> 4) * 8;
            const float* W = m ? Wo : Wr;
            f16x8 v;
            #pragma unroll
            for (int j = 0; j < 8; ++j) v[j] = (_Float16)W[(kb + j) * 64 + col];
            *(f16x8*)&out[(size_t)i * 8] = v;
        }
        return;
    }
    __shared__ int hist[NBUCKET];
    for (int i = threadIdx.x; i < NBUCKET; i += 256) hist[i] = 0;
    __syncthreads();
    int base = blockIdx.x * CHUNK;
    int n = min(CHUNK, N_EDGES - base);
    for (int k = threadIdx.x; k < n; k += 256) {
        int d = dst[base + k];
        atomicAdd(&hist[d >> 8], 1);
        atomicAdd(&counts[d], 1);
    }
    __syncthreads();
    for (int i = threadIdx.x; i < NBUCKET; i += 256)
        h[i * NCHUNK + blockIdx.x] = hist[i];
}

// ---------------- dual-region hierarchical scan ----------------

__global__ void scan_blocks_dual(int* __restrict__ h, const int* __restrict__ counts,
                                 int* __restrict__ offs, int* __restrict__ blocksums) {
    __shared__ int wsum[4];
    int bid = blockIdx.x, t = threadIdx.x;
    if (bid < SB_A) {
        int i = bid * 256 + t;
        int v = (i < SCAN_N) ? h[i] : 0;
        int e = block_excl_scan(v, wsum);
        if (i < SCAN_N) h[i] = e;
        if (t == 255) blocksums[bid] = e + v;
    } else {
        int j = (bid - SB_A) * 256 + t;
        int v = (j < N_NODES) ? roundup4(counts[j]) : 0;
        int e = block_excl_scan(v, wsum);
        if (j < N_NODES) offs[j] = e;
        if (t == 255) blocksums[bid] = e + v;
    }
}

__global__ void scan_mid(const int* __restrict__ blocksums, int* __restrict__ blockoffs) {
    __shared__ int wsum[4];
    int base = (blockIdx.x == 0) ? 0 : SB_A;
    int n = (blockIdx.x == 0) ? SB_A : SB_B;
    int t = threadIdx.x;
    int v = (t < n) ? blocksums[base + t] : 0;
    int e = block_excl_scan(v, wsum);
    if (t < n) blockoffs[base + t] = e;
}

__global__ void scan_add_dual(int* __restrict__ h, int* __restrict__ offs,
                              const int* __restrict__ counts,
                              const int* __restrict__ blockoffs) {
    int bid = blockIdx.x, t = threadIdx.x;
    if (bid < SB_A) {
        int i = bid * 256 + t;
        if (i < SCAN_N) h[i] += blockoffs[bid];
    } else {
        int j = (bid - SB_A) * 256 + t;
        if (j < N_NODES) {
            int v = offs[j] + blockoffs[bid];
            offs[j] = v;
            if (j == N_NODES - 1) offs[N_NODES] = v + roundup4(counts[j]);
        }
    }
}

// ---------------- pass 2: register-staged LDS bucket sort, coalesced flush ----------------

__launch_bounds__(256, 4)
__global__ void scatter_coarse(const int* __restrict__ src, const int* __restrict__ dst,
                               const float* __restrict__ ew, const int* __restrict__ hs,
                               int2* __restrict__ ecoarse) {
    __shared__ int cnt[NBUCKET];
    __shared__ int excl[NBUCKET];
    __shared__ int cur[NBUCKET];
    __shared__ int gbase[NBUCKET];
    __shared__ int wsum[4];
    __shared__ int2 stage[CHUNK];

    int t = threadIdx.x;
    int base = blockIdx.x * CHUNK;
    int n = min(CHUNK, N_EDGES - base);

    for (int i = t; i < NBUCKET; i += 256) {
        cnt[i] = 0;
        gbase[i] = hs[i * NCHUNK + blockIdx.x];
    }
    __syncthreads();

    int rx[EPT];
    float rw[EPT];
    #pragma unroll
    for (int j = 0; j < EPT; ++j) {
        int k = t + j * 256;
        if (k < n) {
            int e = base + k;
            int d = dst[e];
            rx[j] = (d << 16) | src[e];
            rw[j] = ew[e];
            atomicAdd(&cnt[d >> 8], 1);
        }
    }
    __syncthreads();

    {
        int v = (t < NBUCKET) ? cnt[t] : 0;
        int e = block_excl_scan(v, wsum);
        if (t < NBUCKET) { excl[t] = e; cur[t] = e; }
    }
    __syncthreads();

    #pragma unroll
    for (int j = 0; j < EPT; ++j) {
        int k = t + j * 256;
        if (k < n) {
            int b = ((unsigned)rx[j]) >> 24;
            int p = atomicAdd(&cur[b], 1);
            stage[p] = make_int2(rx[j], __float_as_int(rw[j]));
        }
    }
    __syncthreads();

    for (int k = t; k < n; k += 256) {
        int2 r = stage[k];
        int b = ((unsigned)r.x) >> 24;
        ecoarse[gbase[b] + (k - excl[b])] = r;
    }
}

// ---------------- pass 3: per-bucket fine sort into PADDED CSR ----------------

__launch_bounds__(256)
__global__ void fine_sort(const int* __restrict__ h, const int* __restrict__ offs,
                          const int2* __restrict__ ecoarse, int2* __restrict__ esrt) {
    int b = blockIdx.x, t = threadIdx.x;
    __shared__ int cur[256];
    __shared__ int2 stage[CAP_FINE];
    int bstartU = h[b * NCHUNK];
    int bendU = (b == NBUCKET - 1) ? N_EDGES : h[(b + 1) * NCHUNK];
    int nbU = bendU - bstartU;
    int P = offs[b << 8];
    int nodeEnd = min((b + 1) << 8, N_NODES);
    int plen = offs[nodeEnd] - P;
    int dstv = (b << 8) + t;
    cur[t] = (dstv < N_NODES) ? offs[dstv] - P : 0;
    __syncthreads();
    if (plen <= CAP_FINE) {
        for (int k = t; k < plen; k += 256) stage[k] = make_int2(0, 0);
        __syncthreads();
        for (int k = t; k < nbU; k += 256) {
            int2 r = ecoarse[bstartU + k];
            int d = (((unsigned)r.x) >> 16) & 255;
            int p = atomicAdd(&cur[d], 1);
            stage[p] = make_int2(r.x & 0xFFFF, r.y);
        }
        __syncthreads();
        for (int k = t; k < plen; k += 256) esrt[P + k] = stage[k];
    } else {  // fallback, never expected
        for (int k = t; k < plen; k += 256) esrt[P + k] = make_int2(0, 0);
        __syncthreads();
        for (int k = t; k < nbU; k += 256) {
            int2 r = ecoarse[bstartU + k];
            int d = (((unsigned)r.x) >> 16) & 255;
            int p = atomicAdd(&cur[d], 1);
            esrt[P + p] = make_int2(r.x & 0xFFFF, r.y);
        }
    }
}

// ---------------- bcast via readlane (VALU pipe) ----------------

__device__ __forceinline__ float bcast(float v, int k) {
    return __int_as_float(__builtin_amdgcn_readlane(__float_as_int(v), k));
}

// ---------------- layer 0 fused: gather(13) + dual-GEMM + bias + relu -> fp16 ----------------

__launch_bounds__(256)
__global__ void layer0_fused(const int* __restrict__ offs, const int2* __restrict__ esrt,
                             const float* __restrict__ x, const float* __restrict__ Wrel,
                             const float* __restrict__ bias, const float* __restrict__ Wroot,
                             _Float16* __restrict__ h0) {
    int wid = (blockIdx.x * blockDim.x + threadIdx.x) >> 6;
    int lane = threadIdx.x & 63;
    float wr[13], wo[13];
    #pragma unroll
    for (int k = 0; k < 13; ++k) {
        wr[k] = Wrel[k * 64 + lane];
        wo[k] = Wroot[k * 64 + lane];
    }
    float bc = bias[lane];
    int q = lane >> 4, f = lane & 15;
    int beg = offs[wid], end = offs[wid + 1];
    float acc = 0.f;
    bool fv = (f < 13);
    int i = beg + q;
    for (; i + 4 < end; i += 8) {
        int2 e0 = esrt[i], e1 = esrt[i + 4];
        float v0 = fv ? x[(size_t)e0.x * 13 + f] : 0.f;
        float v1 = fv ? x[(size_t)e1.x * 13 + f] : 0.f;
        acc = fmaf(__int_as_float(e0.y), v0, acc);
        acc = fmaf(__int_as_float(e1.y), v1, acc);
    }
    if (i < end) {
        int2 e = esrt[i];
        float v = fv ? x[(size_t)e.x * 13 + f] : 0.f;
        acc = fmaf(__int_as_float(e.y), v, acc);
    }
    acc += __shfl_xor(acc, 16, 64);
    acc += __shfl_xor(acc, 32, 64);
    float hv = (lane < 13) ? x[(size_t)wid * 13 + lane] : 0.f;
    float a0 = bc, a1 = 0.f, a2 = 0.f, a3 = 0.f;
    #pragma unroll
    for (int k = 0; k + 2 <= 13; k += 2) {
        a0 = fmaf(bcast(acc, k), wr[k], a0);
        a1 = fmaf(bcast(hv, k), wo[k], a1);
        a2 = fmaf(bcast(acc, k + 1), wr[k + 1], a2);
        a3 = fmaf(bcast(hv, k + 1), wo[k + 1], a3);
    }
    a0 = fmaf(bcast(acc, 12), wr[12], a0);
    a1 = fmaf(bcast(hv, 12), wo[12], a1);
    float o = fmaxf((a0 + a2) + (a1 + a3), 0.f);
    h0[(size_t)wid * 64 + lane] = (_Float16)o;
}

// ---------------- fused layer: gather + split-fp16 MFMA dual-GEMM, high-occupancy ----
// LDS only holds aggrHi/aggrLo (10 KB). Weights read per-wave from global (L2-hot,
// coalesced); root rows read directly from global in MFMA phase. Gather: quarter-wave
// per node, 8 edges in flight (unroll 2), hi/lo split done pre-barrier.

template <bool FINAL>
__launch_bounds__(256)
__global__ void layer_fused(const int* __restrict__ offs, const int2* __restrict__ esrt,
                            const _Float16* __restrict__ hin, const _Float16* __restrict__ wfrag_l,
                            const float* __restrict__ bias, _Float16* __restrict__ hout,
                            const float* __restrict__ Wrel4, const float* __restrict__ Wroot4,
                            float* __restrict__ z, float* __restrict__ root) {
    __shared__ __align__(16) _Float16 aggrHi[32][72];
    __shared__ __align__(16) _Float16 aggrLo[32][72];
    __shared__ float zpart[4][32], rpart[4][32];
    int t = threadIdx.x;
    int rowbase = blockIdx.x * 32;
    int w = t >> 6, lane = t & 63;

    // issue B-fragment + bias loads early (overlap with gather)
    f16x8 br0 = *(const f16x8*)&wfrag_l[(size_t)(((0 * 4 + w) * 2 + 0) * 64 + lane) * 8];
    f16x8 br1 = *(const f16x8*)&wfrag_l[(size_t)(((0 * 4 + w) * 2 + 1) * 64 + lane) * 8];
    f16x8 bo0 = *(const f16x8*)&wfrag_l[(size_t)(((1 * 4 + w) * 2 + 0) * 64 + lane) * 8];
    f16x8 bo1 = *(const f16x8*)&wfrag_l[(size_t)(((1 * 4 + w) * 2 + 1) * 64 + lane) * 8];
    int r = lane & 15, kq = lane >> 4;
    float bc = bias[w * 16 + r];
    float w4rv = 0.f, w4ov = 0.f;
    if (FINAL) { w4rv = Wrel4[w * 16 + r]; w4ov = Wroot4[w * 16 + r]; }

    // ---- gather phase ----
    int qw = t >> 4, l = t & 15;
    int hi8 = l >> 3, f8 = l & 7;
    #pragma unroll
    for (int rr = 0; rr < 2; ++rr) {
        int node = rowbase + qw + rr * 16;
        float a[8] = {0.f, 0.f, 0.f, 0.f, 0.f, 0.f, 0.f, 0.f};
        if (node < N_NODES) {
            int beg = offs[node], end = offs[node + 1];
            int i = beg;
            for (; i + 4 < end; i += 8) {
                int4 p0 = *(const int4*)(esrt + i);
                int4 p1 = *(const int4*)(esrt + i + 2);
                int4 p2 = *(const int4*)(esrt + i + 4);
                int4 p3 = *(const int4*)(esrt + i + 6);
                int s0 = hi8 ? p0.z : p0.x; float w0 = __int_as_float(hi8 ? p0.w : p0.y);
                int s1 = hi8 ? p1.z : p1.x; float w1 = __int_as_float(hi8 ? p1.w : p1.y);
                int s2 = hi8 ? p2.z : p2.x; float w2 = __int_as_float(hi8 ? p2.w : p2.y);
                int s3 = hi8 ? p3.z : p3.x; float w3 = __int_as_float(hi8 ? p3.w : p3.y);
                f16x8 r0 = *(const f16x8*)(hin + (size_t)s0 * 64 + f8 * 8);
                f16x8 r1 = *(const f16x8*)(hin + (size_t)s1 * 64 + f8 * 8);
                f16x8 r2 = *(const f16x8*)(hin + (size_t)s2 * 64 + f8 * 8);
                f16x8 r3 = *(const f16x8*)(hin + (size_t)s3 * 64 + f8 * 8);
                #pragma unroll
                for (int j = 0; j < 8; ++j) {
                    a[j] = fmaf(w0, (float)r0[j], a[j]);
                    a[j] = fmaf(w1, (float)r1[j], a[j]);
                    a[j] = fmaf(w2, (float)r2[j], a[j]);
                    a[j] = fmaf(w3, (float)r3[j], a[j]);
                }
            }
            if (i < end) {
                int4 p0 = *(const int4*)(esrt + i);
                int4 p1 = *(const int4*)(esrt + i + 2);
                int s0 = hi8 ? p0.z : p0.x; float w0 = __int_as_float(hi8 ? p0.w : p0.y);
                int s1 = hi8 ? p1.z : p1.x; float w1 = __int_as_float(hi8 ? p1.w : p1.y);
                f16x8 r0 = *(const f16x8*)(hin + (size_t)s0 * 64 + f8 * 8);
                f16x8 r1 = *(const f16x8*)(hin + (size_t)s1 * 64 + f8 * 8);
                #pragma unroll
                for (int j = 0; j < 8; ++j) {
                    a[j] = fmaf(w0, (float)r0[j], a[j]);
                    a[j] = fmaf(w1, (float)r1[j], a[j]);
                }
            }
        }
        #pragma unroll
        for (int j = 0; j < 8; ++j) a[j] += __shfl_xor(a[j], 8, 64);
        // hi8=0 lane writes hi, hi8=1 lane writes lo residual
        f16x8 wv;
        #pragma unroll
        for (int j = 0; j < 8; ++j) {
            _Float16 hh = (_Float16)a[j];
            wv[j] = hi8 ? (_Float16)(a[j] - (float)hh) : hh;
        }
        int row = qw + rr * 16;
        _Float16* dstp = hi8 ? &aggrLo[row][f8 * 8] : &aggrHi[row][f8 * 8];
        *(f16x8*)dstp = wv;
    }
    __syncthreads();

    // ---- MFMA phase: wave w owns column tile ct=w ----
    #pragma unroll
    for (int g = 0; g < 2; ++g) {
        int lr = g * 16 + r;
        int grow = min(rowbase + lr, N_NODES - 1);
        f32x4 acc = {bc, bc, bc, bc};
        {
            f16x8 Ah = *(const f16x8*)&aggrHi[lr][0 * 32 + kq * 8];
            f16x8 Al = *(const f16x8*)&aggrLo[lr][0 * 32 + kq * 8];
            f16x8 Ar = *(const f16x8*)&hin[(size_t)grow * 64 + 0 * 32 + kq * 8];
            acc = __builtin_amdgcn_mfma_f32_16x16x32_f16(Ah, br0, acc, 0, 0, 0);
            acc = __builtin_amdgcn_mfma_f32_16x16x32_f16(Al, br0, acc, 0, 0, 0);
            acc = __builtin_amdgcn_mfma_f32_16x16x32_f16(Ar, bo0, acc, 0, 0, 0);
        }
        {
            f16x8 Ah = *(const f16x8*)&aggrHi[lr][1 * 32 + kq * 8];
            f16x8 Al = *(const f16x8*)&aggrLo[lr][1 * 32 + kq * 8];
            f16x8 Ar = *(const f16x8*)&hin[(size_t)grow * 64 + 1 * 32 + kq * 8];
            acc = __builtin_amdgcn_mfma_f32_16x16x32_f16(Ah, br1, acc, 0, 0, 0);
            acc = __builtin_amdgcn_mfma_f32_16x16x32_f16(Al, br1, acc, 0, 0, 0);
            acc = __builtin_amdgcn_mfma_f32_16x16x32_f16(Ar, bo1, acc, 0, 0, 0);
        }
        if (FINAL) {
            #pragma unroll
            for (int j = 0; j < 4; ++j) {
                float o = fmaxf(acc[j], 0.f);
                float zz = o * w4rv, rv = o * w4ov;
                #pragma unroll
                for (int m = 1; m < 16; m <<= 1) {
                    zz += __shfl_xor(zz, m, 64);
                    rv += __shfl_xor(rv, m, 64);
                }
                if (r == 0) {
                    int lrow = g * 16 + (lane >> 4) * 4 + j;
                    zpart[w][lrow] = zz;
                    rpart[w][lrow] = rv;
                }
            }
        } else {
            #pragma unroll
            for (int j = 0; j < 4; ++j) {
                int row = rowbase + g * 16 + (lane >> 4) * 4 + j;
                if (row < N_NODES)
                    hout[(size_t)row * 64 + w * 16 + r] = (_Float16)fmaxf(acc[j], 0.f);
            }
        }
    }
    if (FINAL) {
        __syncthreads();
        if (t < 32) {
            int row = rowbase + t;
            if (row < N_NODES) {
                z[row] = zpart[0][t] + zpart[1][t] + zpart[2][t] + zpart[3][t];
                root[row] = rpart[0][t] + rpart[1][t] + rpart[2][t] + rpart[3][t];
            }
        }
    }
}

// ---------------- final scalar aggregation + sigmoid (4 lanes per node) ----------------

__launch_bounds__(256)
__global__ void final_aggr(const int* __restrict__ offs, const int2* __restrict__ esrt,
                           const float* __restrict__ z, const float* __restrict__ root,
                           const float* __restrict__ b4, float* __restrict__ out) {
    int tid = blockIdx.x * blockDim.x + threadIdx.x;
    int node = tid >> 2, g = tid & 3;
    if (node >= N_NODES) return;
    int beg = offs[node], end = offs[node + 1];
    float a = 0.f;
    int i = beg + g;
    for (; i + 4 < end; i += 8) {
        int2 e0 = esrt[i], e1 = esrt[i + 4];
        a = fmaf(__int_as_float(e0.y), z[e0.x], a);
        a = fmaf(__int_as_float(e1.y), z[e1.x], a);
    }
    if (i < end) {
        int2 e = esrt[i];
        a = fmaf(__int_as_float(e.y), z[e.x], a);
    }
    a += __shfl_xor(a, 1, 64);
    a += __shfl_xor(a, 2, 64);
    if (g == 0) {
        float v = a + b4[0] + root[node];
        out[node] = 1.f / (1.f + expf(-v));
    }
}

// ---------------- launch ----------------

extern "C" void kernel_launch(void* const* d_in, const int* in_sizes, int n_in,
                              void* d_out, int out_size, void* d_ws, size_t ws_size,
                              hipStream_t stream) {
    const float* x = (const float*)d_in[0];
    const int* eidx = (const int*)d_in[1];
    const float* ew = (const float*)d_in[2];
    const float* Wrel[5];
    const float* brel[5];
    const float* Wroot[5];
    for (int i = 0; i < 5; ++i) {
        Wrel[i] = (const float*)d_in[3 + 3 * i];
        brel[i] = (const float*)d_in[4 + 3 * i];
        Wroot[i] = (const float*)d_in[5 + 3 * i];
    }
    const int* src = eidx;
    const int* dst = eidx + N_EDGES;
    float* out = (float*)d_out;

    char* ws = (char*)d_ws;
    size_t off = 0;
    auto alloc = [&](size_t bytes) -> void* {
        void* p = ws + off;
        off = (off + bytes + 255) & ~(size_t)255;
        return p;
    };
    int* h = (int*)alloc((size_t)(SCAN_N + 256) * 4);
    int* blocksums = (int*)alloc(512 * 4);
    int* blockoffs = (int*)alloc(512 * 4);
    int* counts = (int*)alloc((size_t)N_NODES * 4);
    int* offs = (int*)alloc((size_t)(N_NODES + 1) * 4);
    int2* esrt = (int2*)alloc((size_t)MAXEPAD * 8);
    _Float16* h0 = (_Float16*)alloc((size_t)N_NODES * 64 * 2);
    _Float16* h1 = (_Float16*)alloc((size_t)N_NODES * 64 * 2);
    _Float16* wfrag = (_Float16*)alloc((size_t)3 * 8192 * 2);
    float* z = (float*)alloc((size_t)N_NODES * 4);
    float* root = (float*)alloc((size_t)N_NODES * 4);
    int2* ecoarse = (int2*)h0;  // disjoint lifetime: sort phase only
    (void)ws_size; (void)in_sizes; (void)n_in; (void)out_size;

    // ---- CSR build: counting sort with rows padded to multiple of 4 (+fused wconv) ----
    hipMemsetAsync(counts, 0, (size_t)N_NODES * 4, stream);
    hist_kernel<<<NCHUNK + 3, 256, 0, stream>>>(dst, h, counts,
                                                Wrel[1], Wroot[1], Wrel[2], Wroot[2],
                                                Wrel[3], Wroot[3], wfrag);
    scan_blocks_dual<<<SB_A + SB_B, 256, 0, stream>>>(h, counts, offs, blocksums);
    scan_mid<<<2, 256, 0, stream>>>(blocksums, blockoffs);
    scan_add_dual<<<SB_A + SB_B, 256, 0, stream>>>(h, offs, counts, blockoffs);
    scatter_coarse<<<NCHUNK, 256, 0, stream>>>(src, dst, ew, h, ecoarse);
    fine_sort<<<NBUCKET, 256, 0, stream>>>(h, offs, ecoarse, esrt);

    const int NODE_BLOCKS = N_NODES * 64 / 256;  // 12500
    const int FB = (N_NODES + 31) / 32;          // 1563

    // ---- layer 0 (fused gather13 + VALU GEMM) -> h0 fp16 ----
    layer0_fused<<<NODE_BLOCKS, 256, 0, stream>>>(offs, esrt, x, Wrel[0], brel[0], Wroot[0], h0);

    // ---- layers 1..3 fused gather + MFMA ----
    layer_fused<false><<<FB, 256, 0, stream>>>(offs, esrt, h0, wfrag, brel[1], h1,
                                               nullptr, nullptr, nullptr, nullptr);
    layer_fused<false><<<FB, 256, 0, stream>>>(offs, esrt, h1, wfrag + 8192, brel[2], h0,
                                               nullptr, nullptr, nullptr, nullptr);
    layer_fused<true><<<FB, 256, 0, stream>>>(offs, esrt, h0, wfrag + 16384, brel[3], nullptr,
                                              Wrel[4], Wroot[4], z, root);

    // ---- layer 4 scalar aggregation + sigmoid ----
    final_aggr<<<(N_NODES * 4 + 255) / 256, 256, 0, stream>>>(offs, esrt, z, root, brel[4], out);
}